// Round 14
// baseline (298.344 us; speedup 1.0000x reference)
//
#include <hip/hip_runtime.h>
#include <hip/hip_bf16.h>

#define NN 100000   // nodes
#define NE 1600000  // edges
#define NG 1000     // graphs
#define NBK 196     // dst buckets of 512 nodes (196*512 >= NN)
#define BSH 9       // bucket shift
#define SLOT 10240  // slack region per bucket (mean 8192 + 4-align padding)

typedef short short8 __attribute__((ext_vector_type(8)));
typedef float f32x4 __attribute__((ext_vector_type(4)));
typedef float f32x2 __attribute__((ext_vector_type(2)));

static inline int cdiv(int a, int b) { return (a + b - 1) / b; }

// f32 -> bf16 (RNE) and helpers
__device__ __forceinline__ unsigned short f2b(float f) {
    unsigned int u = __float_as_uint(f);
    u += 0x7fff + ((u >> 16) & 1);
    return (unsigned short)(u >> 16);
}
__device__ __forceinline__ unsigned int pack2(float lo, float hi) {
    return (unsigned int)f2b(lo) | ((unsigned int)f2b(hi) << 16);
}

// fp8 e4m3 (OCP) hardware converts; word select must be an immediate constant
template <int W>
__device__ __forceinline__ f32x2 f8_2f(unsigned int v) {
    return __builtin_amdgcn_cvt_pk_f32_fp8((int)v, W);
}
__device__ __forceinline__ unsigned int f2f8_lo(float a, float b, unsigned int old) {
    return (unsigned int)__builtin_amdgcn_cvt_pk_fp8_f32(a, b, (int)old, false);
}
__device__ __forceinline__ unsigned int f2f8_hi(float a, float b, unsigned int old) {
    return (unsigned int)__builtin_amdgcn_cvt_pk_fp8_f32(a, b, (int)old, true);
}

// ------------------------------------------------- prep: W transpose + cursors + permuted biases
// Permuted byte order for fp8 rows: byte q holds col (q&7)*16 + (q>>3).
__global__ __launch_bounds__(256) void k_prep(const float* __restrict__ W1,
                                              const float* __restrict__ W2,
                                              const float* __restrict__ b1,
                                              const float* __restrict__ b2,
                                              unsigned short* __restrict__ Wt1,
                                              unsigned short* __restrict__ Wt2,
                                              float* __restrict__ b1p,
                                              float* __restrict__ b2p,
                                              int* __restrict__ gcur) {
    int b = blockIdx.x, t = threadIdx.x;
    if (b < 128) {
        if (t < 128) Wt1[b * 128 + t] = f2b(W1[t * 128 + b]);
        else         Wt2[b * 128 + (t - 128)] = f2b(W2[(t - 128) * 128 + b]);
    } else {
        if (t < NBK) gcur[t] = t * SLOT;
        if (t < 128) {
            int c = (t & 7) * 16 + (t >> 3);  // col held at permuted position t
            b1p[t] = b1[c];
            b2p[t] = b2[c];
        }
    }
}

// -------------------------------------------------------- two-phase binning
__global__ __launch_bounds__(256) void k_bin2(const int* __restrict__ row,
                                              const int* __restrict__ col,
                                              int* __restrict__ gcur,
                                              unsigned int* __restrict__ tmp) {
    __shared__ int cnt[NBK];
    __shared__ int gbase[NBK];
    int t = threadIdx.x;
    if (t < NBK) cnt[t] = 0;
    __syncthreads();
    const int q0 = blockIdx.x * 1000;  // int4 index base (4000 edges)
    const int4* col4 = (const int4*)col;
    const int4* row4 = (const int4*)row;
#pragma unroll
    for (int it = 0; it < 4; it++) {
        int idx = it * 256 + t;
        if (idx < 1000) {
            int4 c = col4[q0 + idx];
            atomicAdd(&cnt[c.x >> BSH], 1);
            atomicAdd(&cnt[c.y >> BSH], 1);
            atomicAdd(&cnt[c.z >> BSH], 1);
            atomicAdd(&cnt[c.w >> BSH], 1);
        }
    }
    __syncthreads();
    if (t < NBK) {
        gbase[t] = atomicAdd(&gcur[t], cnt[t]);
        cnt[t] = 0;  // becomes local cursor
    }
    __syncthreads();
#pragma unroll
    for (int it = 0; it < 4; it++) {
        int idx = it * 256 + t;
        if (idx < 1000) {
            int4 c = col4[q0 + idx];
            int4 r = row4[q0 + idx];
            int d, s, b, p;
            d = c.x; s = r.x; b = d >> BSH; p = atomicAdd(&cnt[b], 1);
            tmp[gbase[b] + p] = ((unsigned int)(d & 511) << 17) | (unsigned int)s;
            d = c.y; s = r.y; b = d >> BSH; p = atomicAdd(&cnt[b], 1);
            tmp[gbase[b] + p] = ((unsigned int)(d & 511) << 17) | (unsigned int)s;
            d = c.z; s = r.z; b = d >> BSH; p = atomicAdd(&cnt[b], 1);
            tmp[gbase[b] + p] = ((unsigned int)(d & 511) << 17) | (unsigned int)s;
            d = c.w; s = r.w; b = d >> BSH; p = atomicAdd(&cnt[b], 1);
            tmp[gbase[b] + p] = ((unsigned int)(d & 511) << 17) | (unsigned int)s;
        }
    }
}

// -------------------------------------------------------- per-bucket CSR
// 1024 threads/block: 196 blocks can't fill 256 CUs, so use 16 waves/block
// for latency hiding; all phase loops shorten 4x vs the 256-thread version.
__global__ __launch_bounds__(1024) void k_bucket(const unsigned int* __restrict__ tmp,
                                                 const int* __restrict__ gcur,
                                                 int* __restrict__ off,
                                                 int* __restrict__ degw,
                                                 float* __restrict__ dinv,
                                                 int* __restrict__ csr_src) {
    __shared__ int cnt[512];
    __shared__ int loff[512];
    __shared__ int sh[256];
    int b = blockIdx.x, t = threadIdx.x;
    int j0 = b << BSH;
    int nd = min(512, NN - j0);
    int rb = b * SLOT;
    int m = gcur[b] - rb;
    if (t < 512) cnt[t] = 0;
    __syncthreads();
    for (int i = t; i < m; i += 1024)
        atomicAdd(&cnt[tmp[rb + i] >> 17], 1);
    __syncthreads();
    int r0 = 0, r1 = 0, p0 = 0, ts = 0;
    if (t < 256) {
        r0 = cnt[2 * t]; r1 = cnt[2 * t + 1];
        p0 = (r0 + 3) & ~3;
        int p1 = (r1 + 3) & ~3;  // pad to 4-entry alignment
        ts = p0 + p1;
        sh[t] = ts;
    }
    __syncthreads();
    for (int d = 1; d < 256; d <<= 1) {
        int u = (t >= d && t < 256) ? sh[t - d] : 0;
        __syncthreads();
        if (t < 256) sh[t] += u;
        __syncthreads();
    }
    if (t < 256) {
        int ex = sh[t] - ts;
        loff[2 * t] = ex;
        loff[2 * t + 1] = ex + p0;
    }
    __syncthreads();
    for (int j = t; j < nd; j += 1024) {
        int o = rb + loff[j];
        int dg = cnt[j];
        off[j0 + j] = o;
        degw[j0 + j] = dg;
        dinv[j0 + j] = rsqrtf((float)(dg + 1));  // +1 self-loop
        cnt[j] = o;  // becomes cursor
    }
    __syncthreads();
    for (int i = t; i < m; i += 1024) {
        unsigned int e = tmp[rb + i];
        int d = e >> 17;
        int s = (int)(e & 0x1FFFFu);
        int p = atomicAdd(&cnt[d], 1);
        csr_src[p] = s;
    }
}

// ---------------------------------------------------------------- MFMA GEMM
// Hs8[r] = fp8( dinv[r] * (A @ Wt^T) row r ), PERMUTED byte order (q=n16*8+ct).
template <bool AF32>
__global__ __launch_bounds__(256) void k_gemm(const void* __restrict__ Ap,
                                              const unsigned short* __restrict__ Wt,
                                              const float* __restrict__ dinv,
                                              unsigned char* __restrict__ Hs8) {
    __shared__ __align__(16) unsigned short Ws[128 * 128];  // 32 KB
    int t = threadIdx.x;
#pragma unroll
    for (int i = 0; i < 8; i++) {
        int id = t + i * 256;
        int n = id >> 4, c = id & 15;
        *(short8*)((char*)Ws + n * 256 + ((c ^ (n & 15)) << 4)) =
            *(const short8*)(Wt + n * 128 + c * 8);
    }
    __syncthreads();

    int lane = t & 63, wid = t >> 6;
    int n16 = lane & 15, quad = lane >> 4;
    int row_base = blockIdx.x * 128 + wid * 32;

    short8 a[2][4];
#pragma unroll
    for (int rt = 0; rt < 2; rt++) {
        int r = row_base + rt * 16 + n16;
        if (r > NN - 1) r = NN - 1;
        if (AF32) {
            const float* ap = (const float*)Ap + (size_t)r * 128 + quad * 8;
#pragma unroll
            for (int ks = 0; ks < 4; ks++) {
                float4 v0 = *(const float4*)(ap + ks * 32);
                float4 v1 = *(const float4*)(ap + ks * 32 + 4);
                uint4 up;
                up.x = pack2(v0.x, v0.y); up.y = pack2(v0.z, v0.w);
                up.z = pack2(v1.x, v1.y); up.w = pack2(v1.z, v1.w);
                a[rt][ks] = *(short8*)&up;
            }
        } else {
            const unsigned short* ap = (const unsigned short*)Ap + (size_t)r * 128 + quad * 8;
#pragma unroll
            for (int ks = 0; ks < 4; ks++)
                a[rt][ks] = *(const short8*)(ap + ks * 32);
        }
    }

    f32x4 acc[2][8];
#pragma unroll
    for (int rt = 0; rt < 2; rt++)
#pragma unroll
        for (int ct = 0; ct < 8; ct++)
            acc[rt][ct] = (f32x4){0.f, 0.f, 0.f, 0.f};

#pragma unroll
    for (int ks = 0; ks < 4; ks++) {
#pragma unroll
        for (int ct = 0; ct < 8; ct++) {
            short8 b = *(const short8*)((const char*)Ws +
                        (ct * 16 + n16) * 256 + ((((ks << 2) + quad) ^ n16) << 4));
            acc[0][ct] = __builtin_amdgcn_mfma_f32_16x16x32_bf16(a[0][ks], b, acc[0][ct], 0, 0, 0);
            acc[1][ct] = __builtin_amdgcn_mfma_f32_16x16x32_bf16(a[1][ks], b, acc[1][ct], 0, 0, 0);
        }
    }

    // epilogue: thread holds cols ct*16+n16 of row -> permuted bytes n16*8+ct
#pragma unroll
    for (int rt = 0; rt < 2; rt++) {
#pragma unroll
        for (int reg = 0; reg < 4; reg++) {
            int row = row_base + rt * 16 + quad * 4 + reg;
            if (row < NN) {
                float di = dinv[row];
                unsigned int u0 = 0, u1 = 0;
                u0 = f2f8_lo(acc[rt][0][reg] * di, acc[rt][1][reg] * di, u0);
                u0 = f2f8_hi(acc[rt][2][reg] * di, acc[rt][3][reg] * di, u0);
                u1 = f2f8_lo(acc[rt][4][reg] * di, acc[rt][5][reg] * di, u1);
                u1 = f2f8_hi(acc[rt][6][reg] * di, acc[rt][7][reg] * di, u1);
                uint2 o; o.x = u0; o.y = u1;
                ((uint2*)(Hs8 + (size_t)row * 128))[n16] = o;
            }
        }
    }
}

// ---------------------------------------------------------------- aggregation
// out[i] = relu( dinv[i] * (Hs[i] + sum_e Hs[src_e]) + bias )
// Hs rows: fp8 permuted, 128B. 8 subgroups x 8 lanes, uint4 (16B) per lane ->
// one gather instruction covers 8 rows (1KB); int2 index loads.
// Lane li holds permuted bytes q = li*16 + j (j=0..15) -> acc[j].
template <bool FP8OUT>
__global__ __launch_bounds__(256) void k_agg(const uint4* __restrict__ H4,
                                             const int* __restrict__ off,
                                             const int* __restrict__ degw,
                                             const int* __restrict__ csr_src,
                                             const float* __restrict__ dinv,
                                             const float* __restrict__ biasp,
                                             void* __restrict__ outp) {
    int node = blockIdx.x * 4 + (threadIdx.x >> 6);
    int lane = threadIdx.x & 63;
    int sub = lane >> 3, li = lane & 7;
    float acc[16];
#pragma unroll
    for (int j = 0; j < 16; j++) acc[j] = 0.f;
    f32x2 p;
#define ACC16(V) { \
    p = f8_2f<0>((V).x); acc[0] += p.x;  acc[1] += p.y;  \
    p = f8_2f<1>((V).x); acc[2] += p.x;  acc[3] += p.y;  \
    p = f8_2f<0>((V).y); acc[4] += p.x;  acc[5] += p.y;  \
    p = f8_2f<1>((V).y); acc[6] += p.x;  acc[7] += p.y;  \
    p = f8_2f<0>((V).z); acc[8] += p.x;  acc[9] += p.y;  \
    p = f8_2f<1>((V).z); acc[10] += p.x; acc[11] += p.y; \
    p = f8_2f<0>((V).w); acc[12] += p.x; acc[13] += p.y; \
    p = f8_2f<1>((V).w); acc[14] += p.x; acc[15] += p.y; }
    if (sub == 0) {  // self term (already dinv-scaled)
        uint4 v = H4[(size_t)node * 8 + li];
        ACC16(v)
    }
    int e0 = off[node], e1 = e0 + degw[node];
    int e = e0;
    for (; e + 16 <= e1; e += 16) {  // subgroup s handles edges e+2s, e+2s+1
        int2 sv = *(const int2*)(csr_src + e + sub * 2);
        uint4 w0 = H4[(size_t)sv.x * 8 + li];
        uint4 w1 = H4[(size_t)sv.y * 8 + li];
        ACC16(w0) ACC16(w1)
    }
    for (; e + 8 <= e1; e += 8) {
        int s1 = csr_src[e + sub];
        uint4 wv = H4[(size_t)s1 * 8 + li];
        ACC16(wv)
    }
    for (; e < e1; e += 8) {  // tail <= 4 (segments padded to 4)
        int ee = e + sub;
        if (ee < e1) {
            int s1 = csr_src[ee];
            uint4 wv = H4[(size_t)s1 * 8 + li];
            ACC16(wv)
        }
    }
#undef ACC16
    // butterfly across the 8 subgroups
#pragma unroll
    for (int j = 0; j < 16; j++) {
        acc[j] += __shfl_xor(acc[j], 8);
        acc[j] += __shfl_xor(acc[j], 16);
        acc[j] += __shfl_xor(acc[j], 32);
    }
    if (sub == 0) {
        float di = dinv[node];
        const float4* b4 = (const float4*)biasp;  // permuted bias
        float r[16];
#pragma unroll
        for (int c4 = 0; c4 < 4; c4++) {
            float4 bb = b4[li * 4 + c4];
            r[c4 * 4 + 0] = fmaxf(fmaf(di, acc[c4 * 4 + 0], bb.x), 0.f);
            r[c4 * 4 + 1] = fmaxf(fmaf(di, acc[c4 * 4 + 1], bb.y), 0.f);
            r[c4 * 4 + 2] = fmaxf(fmaf(di, acc[c4 * 4 + 2], bb.z), 0.f);
            r[c4 * 4 + 3] = fmaxf(fmaf(di, acc[c4 * 4 + 3], bb.w), 0.f);
        }
        if (FP8OUT) {  // fp8 permuted: bytes q=li*16+j in j order
            unsigned int u_;
            uint4 o;
            u_ = 0; u_ = f2f8_lo(r[0], r[1], u_);   u_ = f2f8_hi(r[2], r[3], u_);   o.x = u_;
            u_ = 0; u_ = f2f8_lo(r[4], r[5], u_);   u_ = f2f8_hi(r[6], r[7], u_);   o.y = u_;
            u_ = 0; u_ = f2f8_lo(r[8], r[9], u_);   u_ = f2f8_hi(r[10], r[11], u_); o.z = u_;
            u_ = 0; u_ = f2f8_lo(r[12], r[13], u_); u_ = f2f8_hi(r[14], r[15], u_); o.w = u_;
            ((uint4*)outp)[(size_t)node * 8 + li] = o;
        } else {
            // bf16 natural: byte q=li*16+j -> col (j&7)*16 + li*2 + (j>>3);
            // chunk b: adjacent cols (b*16+li*2, +1) = (r[b], r[b+8]) as one uint
            unsigned int* ob = (unsigned int*)((unsigned short*)outp + (size_t)node * 128);
#pragma unroll
            for (int b = 0; b < 8; b++)
                ob[b * 8 + li] = pack2(r[b], r[8 + b]);
        }
    }
}

// ------------------------------------------------- fused mean-pool + head MLP
// A2: fp8 permuted. part[] indexed by permuted byte q; hc[] unpermutes.
__global__ __launch_bounds__(256) void k_poolhead(const unsigned char* __restrict__ A,
                                                  const int* __restrict__ batch,
                                                  const float* __restrict__ u,
                                                  const float* __restrict__ Wh1,
                                                  const float* __restrict__ bh1,
                                                  const float* __restrict__ Wh2,
                                                  const float* __restrict__ bh2,
                                                  float* __restrict__ out) {
    int g = blockIdx.x, t = threadIdx.x;
    int lo = 0, hi = NN;
    while (lo < hi) { int m = (lo + hi) >> 1; if (batch[m] < g) lo = m + 1; else hi = m; }
    int start = lo;
    hi = NN;
    while (lo < hi) { int m = (lo + hi) >> 1; if (batch[m] < g + 1) lo = m + 1; else hi = m; }
    int end = lo;

    int li = t & 7;    // 16-byte chunk of the 128B row
    int ri = t >> 3;   // row offset 0..31
    float acc[16];
#pragma unroll
    for (int j = 0; j < 16; j++) acc[j] = 0.f;
    f32x2 p;
    for (int i = start + ri; i < end; i += 32) {
        uint4 v = ((const uint4*)A)[(size_t)i * 8 + li];
#define UP(VV, base) p = f8_2f<0>(VV); acc[base] += p.x; acc[base+1] += p.y; \
                     p = f8_2f<1>(VV); acc[base+2] += p.x; acc[base+3] += p.y;
        UP(v.x, 0) UP(v.y, 4) UP(v.z, 8) UP(v.w, 12)
#undef UP
    }
#pragma unroll
    for (int j = 0; j < 16; j++) {
        acc[j] += __shfl_xor(acc[j], 8);
        acc[j] += __shfl_xor(acc[j], 16);
        acc[j] += __shfl_xor(acc[j], 32);
    }
    __shared__ float part[4][128];
    __shared__ float hc[192];
    __shared__ float tt[128];
    int w = t >> 6;
    if ((t & 63) < 8) {
#pragma unroll
        for (int j = 0; j < 16; j++) part[w][li * 16 + j] = acc[j];  // index = byte q
    }
    __syncthreads();
    float cntf = (float)max(end - start, 1);
    if (t < 128) {
        int q = (t & 15) * 8 + (t >> 4);  // permuted position of col t
        hc[t] = (part[0][q] + part[1][q] + part[2][q] + part[3][q]) / cntf;
    } else if (t < 192) {
        hc[t] = u[g * 64 + (t - 128)];
    }
    __syncthreads();
    if (t < 128) {
        float a2 = bh1[t];
        for (int k = 0; k < 192; k++) a2 = fmaf(hc[k], Wh1[k * 128 + t], a2);
        tt[t] = fmaxf(a2, 0.f);
    }
    __syncthreads();
    if (t < 2) {
        float o = bh2[t];
        for (int c2 = 0; c2 < 128; c2++) o = fmaf(tt[c2], Wh2[c2 * 2 + t], o);
        out[g * 2 + t] = o;
    }
}

// ---------------------------------------------------------------- launcher
extern "C" void kernel_launch(void* const* d_in, const int* in_sizes, int n_in,
                              void* d_out, int out_size, void* d_ws, size_t ws_size,
                              hipStream_t stream) {
    const float* x   = (const float*)d_in[0];
    const int*   ei  = (const int*)d_in[1];
    const int*   row = ei;        // edge_index[0] = src
    const int*   col = ei + NE;   // edge_index[1] = dst
    const float* u   = (const float*)d_in[2];
    const int*   batch = (const int*)d_in[3];
    const float* W1  = (const float*)d_in[5];
    const float* b1  = (const float*)d_in[6];
    const float* W2  = (const float*)d_in[7];
    const float* b2  = (const float*)d_in[8];
    const float* Wh1 = (const float*)d_in[9];
    const float* bh1 = (const float*)d_in[10];
    const float* Wh2 = (const float*)d_in[11];
    const float* bh2 = (const float*)d_in[12];
    float* out = (float*)d_out;

    char* ws = (char*)d_ws;
    size_t o = 0;
    auto alloc = [&](size_t bytes) -> void* {
        void* p = ws + o;
        o += (bytes + 511) & ~(size_t)511;
        return p;
    };
    unsigned char*  Hs8 = (unsigned char*)alloc((size_t)NN * 128);       // fp8 permuted
    unsigned short* A1b = (unsigned short*)alloc((size_t)NN * 128 * 2);  // bf16 natural
    unsigned char*  A2b = (unsigned char*)alloc((size_t)NN * 128);       // fp8 permuted
    unsigned short* Wt1 = (unsigned short*)alloc((size_t)128 * 128 * 2);
    unsigned short* Wt2 = (unsigned short*)alloc((size_t)128 * 128 * 2);
    float* b1p    = (float*)alloc((size_t)128 * 4);
    float* b2p    = (float*)alloc((size_t)128 * 4);
    float* dinv   = (float*)alloc((size_t)NN * 4);
    int*   off    = (int*)alloc((size_t)NN * 4);
    int*   degw   = (int*)alloc((size_t)NN * 4);
    int*   csr_src= (int*)alloc((size_t)NBK * SLOT * 4);
    unsigned int* tmp = (unsigned int*)alloc((size_t)NBK * SLOT * 4);
    int*   gcur   = (int*)alloc((size_t)256 * 4);

    // --- prep (W transpose + cursors + permuted biases) & CSR build ---
    k_prep<<<129, 256, 0, stream>>>(W1, W2, b1, b2, Wt1, Wt2, b1p, b2p, gcur);
    k_bin2<<<400, 256, 0, stream>>>(row, col, gcur, tmp);
    k_bucket<<<NBK, 1024, 0, stream>>>(tmp, gcur, off, degw, dinv, csr_src);

    // --- layer 1 (f32 input, in-register bf16 pack; fp8 H) ---
    k_gemm<true><<<cdiv(NN, 128), 256, 0, stream>>>((const void*)x, Wt1, dinv, Hs8);
    k_agg<false><<<NN / 4, 256, 0, stream>>>((const uint4*)Hs8, off, degw, csr_src,
                                             dinv, b1p, (void*)A1b);
    // --- layer 2 ---
    k_gemm<false><<<cdiv(NN, 128), 256, 0, stream>>>((const void*)A1b, Wt2, dinv, Hs8);
    k_agg<true><<<NN / 4, 256, 0, stream>>>((const uint4*)Hs8, off, degw, csr_src,
                                            dinv, b2p, (void*)A2b);

    // --- fused mean pool + head ---
    k_poolhead<<<NG, 256, 0, stream>>>(A2b, batch, u, Wh1, bh1, Wh2, bh2, out);
}

// Round 15
// 290.660 us; speedup vs baseline: 1.0264x; 1.0264x over previous
//
#include <hip/hip_runtime.h>
#include <hip/hip_bf16.h>

#define NN 100000   // nodes
#define NE 1600000  // edges
#define NG 1000     // graphs
#define NBK 196     // dst buckets of 512 nodes (196*512 >= NN)
#define BSH 9       // bucket shift
#define SLOT 10240  // slack region per bucket (mean 8192 + 4-align padding)

typedef short short8 __attribute__((ext_vector_type(8)));
typedef float f32x4 __attribute__((ext_vector_type(4)));
typedef float f32x2 __attribute__((ext_vector_type(2)));

static inline int cdiv(int a, int b) { return (a + b - 1) / b; }

// f32 -> bf16 (RNE) and helpers
__device__ __forceinline__ unsigned short f2b(float f) {
    unsigned int u = __float_as_uint(f);
    u += 0x7fff + ((u >> 16) & 1);
    return (unsigned short)(u >> 16);
}
__device__ __forceinline__ unsigned int pack2(float lo, float hi) {
    return (unsigned int)f2b(lo) | ((unsigned int)f2b(hi) << 16);
}

// fp8 e4m3 (OCP) hardware converts; word select must be an immediate constant
template <int W>
__device__ __forceinline__ f32x2 f8_2f(unsigned int v) {
    return __builtin_amdgcn_cvt_pk_f32_fp8((int)v, W);
}
__device__ __forceinline__ unsigned int f2f8_lo(float a, float b, unsigned int old) {
    return (unsigned int)__builtin_amdgcn_cvt_pk_fp8_f32(a, b, (int)old, false);
}
__device__ __forceinline__ unsigned int f2f8_hi(float a, float b, unsigned int old) {
    return (unsigned int)__builtin_amdgcn_cvt_pk_fp8_f32(a, b, (int)old, true);
}

// ------------------------------------------------- prep: W transpose + cursors + permuted biases
// Permuted byte order for fp8 rows: byte q holds col (q&7)*16 + (q>>3).
__global__ __launch_bounds__(256) void k_prep(const float* __restrict__ W1,
                                              const float* __restrict__ W2,
                                              const float* __restrict__ b1,
                                              const float* __restrict__ b2,
                                              unsigned short* __restrict__ Wt1,
                                              unsigned short* __restrict__ Wt2,
                                              float* __restrict__ b1p,
                                              float* __restrict__ b2p,
                                              int* __restrict__ gcur) {
    int b = blockIdx.x, t = threadIdx.x;
    if (b < 128) {
        if (t < 128) Wt1[b * 128 + t] = f2b(W1[t * 128 + b]);
        else         Wt2[b * 128 + (t - 128)] = f2b(W2[(t - 128) * 128 + b]);
    } else {
        if (t < NBK) gcur[t] = t * SLOT;
        if (t < 128) {
            int c = (t & 7) * 16 + (t >> 3);  // col held at permuted position t
            b1p[t] = b1[c];
            b2p[t] = b2[c];
        }
    }
}

// -------------------------------------------------------- two-phase binning
__global__ __launch_bounds__(256) void k_bin2(const int* __restrict__ row,
                                              const int* __restrict__ col,
                                              int* __restrict__ gcur,
                                              unsigned int* __restrict__ tmp) {
    __shared__ int cnt[NBK];
    __shared__ int gbase[NBK];
    int t = threadIdx.x;
    if (t < NBK) cnt[t] = 0;
    __syncthreads();
    const int q0 = blockIdx.x * 1000;  // int4 index base (4000 edges)
    const int4* col4 = (const int4*)col;
    const int4* row4 = (const int4*)row;
#pragma unroll
    for (int it = 0; it < 4; it++) {
        int idx = it * 256 + t;
        if (idx < 1000) {
            int4 c = col4[q0 + idx];
            atomicAdd(&cnt[c.x >> BSH], 1);
            atomicAdd(&cnt[c.y >> BSH], 1);
            atomicAdd(&cnt[c.z >> BSH], 1);
            atomicAdd(&cnt[c.w >> BSH], 1);
        }
    }
    __syncthreads();
    if (t < NBK) {
        gbase[t] = atomicAdd(&gcur[t], cnt[t]);
        cnt[t] = 0;  // becomes local cursor
    }
    __syncthreads();
#pragma unroll
    for (int it = 0; it < 4; it++) {
        int idx = it * 256 + t;
        if (idx < 1000) {
            int4 c = col4[q0 + idx];
            int4 r = row4[q0 + idx];
            int d, s, b, p;
            d = c.x; s = r.x; b = d >> BSH; p = atomicAdd(&cnt[b], 1);
            tmp[gbase[b] + p] = ((unsigned int)(d & 511) << 17) | (unsigned int)s;
            d = c.y; s = r.y; b = d >> BSH; p = atomicAdd(&cnt[b], 1);
            tmp[gbase[b] + p] = ((unsigned int)(d & 511) << 17) | (unsigned int)s;
            d = c.z; s = r.z; b = d >> BSH; p = atomicAdd(&cnt[b], 1);
            tmp[gbase[b] + p] = ((unsigned int)(d & 511) << 17) | (unsigned int)s;
            d = c.w; s = r.w; b = d >> BSH; p = atomicAdd(&cnt[b], 1);
            tmp[gbase[b] + p] = ((unsigned int)(d & 511) << 17) | (unsigned int)s;
        }
    }
}

// -------------------------------------------------------- per-bucket CSR
// 1024 threads/block (R14-verified ~10us win): 196 blocks can't fill 256 CUs,
// so 16 waves/block hide latency; phase loops shorten 4x.
__global__ __launch_bounds__(1024) void k_bucket(const unsigned int* __restrict__ tmp,
                                                 const int* __restrict__ gcur,
                                                 int* __restrict__ off,
                                                 int* __restrict__ degw,
                                                 float* __restrict__ dinv,
                                                 int* __restrict__ csr_src) {
    __shared__ int cnt[512];
    __shared__ int loff[512];
    __shared__ int sh[256];
    int b = blockIdx.x, t = threadIdx.x;
    int j0 = b << BSH;
    int nd = min(512, NN - j0);
    int rb = b * SLOT;
    int m = gcur[b] - rb;
    if (t < 512) cnt[t] = 0;
    __syncthreads();
    for (int i = t; i < m; i += 1024)
        atomicAdd(&cnt[tmp[rb + i] >> 17], 1);
    __syncthreads();
    int r0 = 0, r1 = 0, p0 = 0, ts = 0;
    if (t < 256) {
        r0 = cnt[2 * t]; r1 = cnt[2 * t + 1];
        p0 = (r0 + 3) & ~3;
        int p1 = (r1 + 3) & ~3;  // pad to 4-entry alignment
        ts = p0 + p1;
        sh[t] = ts;
    }
    __syncthreads();
    for (int d = 1; d < 256; d <<= 1) {
        int u = (t >= d && t < 256) ? sh[t - d] : 0;
        __syncthreads();
        if (t < 256) sh[t] += u;
        __syncthreads();
    }
    if (t < 256) {
        int ex = sh[t] - ts;
        loff[2 * t] = ex;
        loff[2 * t + 1] = ex + p0;
    }
    __syncthreads();
    for (int j = t; j < nd; j += 1024) {
        int o = rb + loff[j];
        int dg = cnt[j];
        off[j0 + j] = o;
        degw[j0 + j] = dg;
        dinv[j0 + j] = rsqrtf((float)(dg + 1));  // +1 self-loop
        cnt[j] = o;  // becomes cursor
    }
    __syncthreads();
    for (int i = t; i < m; i += 1024) {
        unsigned int e = tmp[rb + i];
        int d = e >> 17;
        int s = (int)(e & 0x1FFFFu);
        int p = atomicAdd(&cnt[d], 1);
        csr_src[p] = s;
    }
}

// ---------------------------------------------------------------- MFMA GEMM
// Hs8[r] = fp8( dinv[r] * (A @ Wt^T) row r ), PERMUTED byte order (q=n16*8+ct).
template <bool AF32>
__global__ __launch_bounds__(256) void k_gemm(const void* __restrict__ Ap,
                                              const unsigned short* __restrict__ Wt,
                                              const float* __restrict__ dinv,
                                              unsigned char* __restrict__ Hs8) {
    __shared__ __align__(16) unsigned short Ws[128 * 128];  // 32 KB
    int t = threadIdx.x;
#pragma unroll
    for (int i = 0; i < 8; i++) {
        int id = t + i * 256;
        int n = id >> 4, c = id & 15;
        *(short8*)((char*)Ws + n * 256 + ((c ^ (n & 15)) << 4)) =
            *(const short8*)(Wt + n * 128 + c * 8);
    }
    __syncthreads();

    int lane = t & 63, wid = t >> 6;
    int n16 = lane & 15, quad = lane >> 4;
    int row_base = blockIdx.x * 128 + wid * 32;

    short8 a[2][4];
#pragma unroll
    for (int rt = 0; rt < 2; rt++) {
        int r = row_base + rt * 16 + n16;
        if (r > NN - 1) r = NN - 1;
        if (AF32) {
            const float* ap = (const float*)Ap + (size_t)r * 128 + quad * 8;
#pragma unroll
            for (int ks = 0; ks < 4; ks++) {
                float4 v0 = *(const float4*)(ap + ks * 32);
                float4 v1 = *(const float4*)(ap + ks * 32 + 4);
                uint4 up;
                up.x = pack2(v0.x, v0.y); up.y = pack2(v0.z, v0.w);
                up.z = pack2(v1.x, v1.y); up.w = pack2(v1.z, v1.w);
                a[rt][ks] = *(short8*)&up;
            }
        } else {
            const unsigned short* ap = (const unsigned short*)Ap + (size_t)r * 128 + quad * 8;
#pragma unroll
            for (int ks = 0; ks < 4; ks++)
                a[rt][ks] = *(const short8*)(ap + ks * 32);
        }
    }

    f32x4 acc[2][8];
#pragma unroll
    for (int rt = 0; rt < 2; rt++)
#pragma unroll
        for (int ct = 0; ct < 8; ct++)
            acc[rt][ct] = (f32x4){0.f, 0.f, 0.f, 0.f};

#pragma unroll
    for (int ks = 0; ks < 4; ks++) {
#pragma unroll
        for (int ct = 0; ct < 8; ct++) {
            short8 b = *(const short8*)((const char*)Ws +
                        (ct * 16 + n16) * 256 + ((((ks << 2) + quad) ^ n16) << 4));
            acc[0][ct] = __builtin_amdgcn_mfma_f32_16x16x32_bf16(a[0][ks], b, acc[0][ct], 0, 0, 0);
            acc[1][ct] = __builtin_amdgcn_mfma_f32_16x16x32_bf16(a[1][ks], b, acc[1][ct], 0, 0, 0);
        }
    }

    // epilogue: thread holds cols ct*16+n16 of row -> permuted bytes n16*8+ct
#pragma unroll
    for (int rt = 0; rt < 2; rt++) {
#pragma unroll
        for (int reg = 0; reg < 4; reg++) {
            int row = row_base + rt * 16 + quad * 4 + reg;
            if (row < NN) {
                float di = dinv[row];
                unsigned int u0 = 0, u1 = 0;
                u0 = f2f8_lo(acc[rt][0][reg] * di, acc[rt][1][reg] * di, u0);
                u0 = f2f8_hi(acc[rt][2][reg] * di, acc[rt][3][reg] * di, u0);
                u1 = f2f8_lo(acc[rt][4][reg] * di, acc[rt][5][reg] * di, u1);
                u1 = f2f8_hi(acc[rt][6][reg] * di, acc[rt][7][reg] * di, u1);
                uint2 o; o.x = u0; o.y = u1;
                ((uint2*)(Hs8 + (size_t)row * 128))[n16] = o;
            }
        }
    }
}

// ---------------------------------------------------------------- aggregation
// out[i] = relu( dinv[i] * (Hs[i] + sum_e Hs[src_e]) + bias )
// R12-frozen formulation (best measured): 4 subgroups x 16 lanes, uint2/lane,
// 16 edges/iter via int4 index loads; fp8 unpack via cvt_pk_f32_fp8.
template <bool FP8OUT>
__global__ __launch_bounds__(256) void k_agg(const uint2* __restrict__ H2,
                                             const int* __restrict__ off,
                                             const int* __restrict__ degw,
                                             const int* __restrict__ csr_src,
                                             const float* __restrict__ dinv,
                                             const float* __restrict__ biasp,
                                             void* __restrict__ outp) {
    int node = blockIdx.x * 4 + (threadIdx.x >> 6);
    int lane = threadIdx.x & 63;
    int sub = lane >> 4, li = lane & 15;
    float2 A0 = {0.f, 0.f}, A1 = {0.f, 0.f}, A2 = {0.f, 0.f}, A3 = {0.f, 0.f};
    f32x2 p;
#define ACC8(V) { \
        p = f8_2f<0>((V).x); A0.x += p.x; A0.y += p.y; \
        p = f8_2f<1>((V).x); A1.x += p.x; A1.y += p.y; \
        p = f8_2f<0>((V).y); A2.x += p.x; A2.y += p.y; \
        p = f8_2f<1>((V).y); A3.x += p.x; A3.y += p.y; }
    if (sub == 0) {  // self term (already dinv-scaled)
        uint2 v = H2[(size_t)node * 16 + li];
        ACC8(v)
    }
    int e0 = off[node], e1 = e0 + degw[node];
    int e = e0;
    for (; e + 16 <= e1; e += 16) {
        int4 sv = *(const int4*)(csr_src + e + sub * 4);
        uint2 w0 = H2[(size_t)sv.x * 16 + li];
        uint2 w1 = H2[(size_t)sv.y * 16 + li];
        uint2 w2 = H2[(size_t)sv.z * 16 + li];
        uint2 w3 = H2[(size_t)sv.w * 16 + li];
        ACC8(w0) ACC8(w1) ACC8(w2) ACC8(w3)
    }
    for (; e + 8 <= e1; e += 8) {
        int2 sv = *(const int2*)(csr_src + e + sub * 2);
        uint2 wA = H2[(size_t)sv.x * 16 + li];
        uint2 wB = H2[(size_t)sv.y * 16 + li];
        ACC8(wA) ACC8(wB)
    }
    for (; e < e1; e += 4) {
        int ee = e + sub;
        if (ee < e1) {
            int s = csr_src[ee];
            uint2 w = H2[(size_t)s * 16 + li];
            ACC8(w)
        }
    }
#undef ACC8
#pragma unroll
    for (int d = 16; d <= 32; d <<= 1) {
        A0.x += __shfl_xor(A0.x, d); A0.y += __shfl_xor(A0.y, d);
        A1.x += __shfl_xor(A1.x, d); A1.y += __shfl_xor(A1.y, d);
        A2.x += __shfl_xor(A2.x, d); A2.y += __shfl_xor(A2.y, d);
        A3.x += __shfl_xor(A3.x, d); A3.y += __shfl_xor(A3.y, d);
    }
    if (sub == 0) {
        float di = dinv[node];
        const float4* b4 = (const float4*)biasp;  // permuted bias
        float4 bA = b4[li * 2], bB = b4[li * 2 + 1];
        float r0 = fmaxf(fmaf(di, A0.x, bA.x), 0.f);  // col  0+li
        float r1 = fmaxf(fmaf(di, A0.y, bA.y), 0.f);  // col 16+li
        float r2 = fmaxf(fmaf(di, A1.x, bA.z), 0.f);
        float r3 = fmaxf(fmaf(di, A1.y, bA.w), 0.f);
        float r4 = fmaxf(fmaf(di, A2.x, bB.x), 0.f);
        float r5 = fmaxf(fmaf(di, A2.y, bB.y), 0.f);
        float r6 = fmaxf(fmaf(di, A3.x, bB.z), 0.f);
        float r7 = fmaxf(fmaf(di, A3.y, bB.w), 0.f);
        if (FP8OUT) {  // fp8 permuted (8B packed store)
            unsigned int u0 = 0, u1 = 0;
            u0 = f2f8_lo(r0, r1, u0); u0 = f2f8_hi(r2, r3, u0);
            u1 = f2f8_lo(r4, r5, u1); u1 = f2f8_hi(r6, r7, u1);
            uint2 o; o.x = u0; o.y = u1;
            ((uint2*)outp)[(size_t)node * 16 + li] = o;
        } else {  // bf16 natural (for GEMM2 A-frags)
            unsigned short* ob = (unsigned short*)outp + (size_t)node * 128 + li;
            ob[0]   = f2b(r0); ob[16]  = f2b(r1); ob[32]  = f2b(r2); ob[48]  = f2b(r3);
            ob[64]  = f2b(r4); ob[80]  = f2b(r5); ob[96]  = f2b(r6); ob[112] = f2b(r7);
        }
    }
}

// ------------------------------------------------- fused mean-pool + head MLP
// A2: fp8 permuted. part[] indexed by permuted byte q; hc[] unpermutes.
__global__ __launch_bounds__(256) void k_poolhead(const unsigned char* __restrict__ A,
                                                  const int* __restrict__ batch,
                                                  const float* __restrict__ u,
                                                  const float* __restrict__ Wh1,
                                                  const float* __restrict__ bh1,
                                                  const float* __restrict__ Wh2,
                                                  const float* __restrict__ bh2,
                                                  float* __restrict__ out) {
    int g = blockIdx.x, t = threadIdx.x;
    int lo = 0, hi = NN;
    while (lo < hi) { int m = (lo + hi) >> 1; if (batch[m] < g) lo = m + 1; else hi = m; }
    int start = lo;
    hi = NN;
    while (lo < hi) { int m = (lo + hi) >> 1; if (batch[m] < g + 1) lo = m + 1; else hi = m; }
    int end = lo;

    int li = t & 7;    // 16-byte chunk of the 128B row
    int ri = t >> 3;   // row offset 0..31
    float acc[16];
#pragma unroll
    for (int j = 0; j < 16; j++) acc[j] = 0.f;
    f32x2 p;
    for (int i = start + ri; i < end; i += 32) {
        uint4 v = ((const uint4*)A)[(size_t)i * 8 + li];
#define UP(VV, base) p = f8_2f<0>(VV); acc[base] += p.x; acc[base+1] += p.y; \
                     p = f8_2f<1>(VV); acc[base+2] += p.x; acc[base+3] += p.y;
        UP(v.x, 0) UP(v.y, 4) UP(v.z, 8) UP(v.w, 12)
#undef UP
    }
#pragma unroll
    for (int j = 0; j < 16; j++) {
        acc[j] += __shfl_xor(acc[j], 8);
        acc[j] += __shfl_xor(acc[j], 16);
        acc[j] += __shfl_xor(acc[j], 32);
    }
    __shared__ float part[4][128];
    __shared__ float hc[192];
    __shared__ float tt[128];
    int w = t >> 6;
    if ((t & 63) < 8) {
#pragma unroll
        for (int j = 0; j < 16; j++) part[w][li * 16 + j] = acc[j];  // index = byte q
    }
    __syncthreads();
    float cntf = (float)max(end - start, 1);
    if (t < 128) {
        int q = (t & 15) * 8 + (t >> 4);  // permuted position of col t
        hc[t] = (part[0][q] + part[1][q] + part[2][q] + part[3][q]) / cntf;
    } else if (t < 192) {
        hc[t] = u[g * 64 + (t - 128)];
    }
    __syncthreads();
    if (t < 128) {
        float a2 = bh1[t];
        for (int k = 0; k < 192; k++) a2 = fmaf(hc[k], Wh1[k * 128 + t], a2);
        tt[t] = fmaxf(a2, 0.f);
    }
    __syncthreads();
    if (t < 2) {
        float o = bh2[t];
        for (int c2 = 0; c2 < 128; c2++) o = fmaf(tt[c2], Wh2[c2 * 2 + t], o);
        out[g * 2 + t] = o;
    }
}

// ---------------------------------------------------------------- launcher
extern "C" void kernel_launch(void* const* d_in, const int* in_sizes, int n_in,
                              void* d_out, int out_size, void* d_ws, size_t ws_size,
                              hipStream_t stream) {
    const float* x   = (const float*)d_in[0];
    const int*   ei  = (const int*)d_in[1];
    const int*   row = ei;        // edge_index[0] = src
    const int*   col = ei + NE;   // edge_index[1] = dst
    const float* u   = (const float*)d_in[2];
    const int*   batch = (const int*)d_in[3];
    const float* W1  = (const float*)d_in[5];
    const float* b1  = (const float*)d_in[6];
    const float* W2  = (const float*)d_in[7];
    const float* b2  = (const float*)d_in[8];
    const float* Wh1 = (const float*)d_in[9];
    const float* bh1 = (const float*)d_in[10];
    const float* Wh2 = (const float*)d_in[11];
    const float* bh2 = (const float*)d_in[12];
    float* out = (float*)d_out;

    char* ws = (char*)d_ws;
    size_t o = 0;
    auto alloc = [&](size_t bytes) -> void* {
        void* p = ws + o;
        o += (bytes + 511) & ~(size_t)511;
        return p;
    };
    unsigned char*  Hs8 = (unsigned char*)alloc((size_t)NN * 128);       // fp8 permuted
    unsigned short* A1b = (unsigned short*)alloc((size_t)NN * 128 * 2);  // bf16 natural
    unsigned char*  A2b = (unsigned char*)alloc((size_t)NN * 128);       // fp8 permuted
    unsigned short* Wt1 = (unsigned short*)alloc((size_t)128 * 128 * 2);
    unsigned short* Wt2 = (unsigned short*)alloc((size_t)128 * 128 * 2);
    float* b1p    = (float*)alloc((size_t)128 * 4);
    float* b2p    = (float*)alloc((size_t)128 * 4);
    float* dinv   = (float*)alloc((size_t)NN * 4);
    int*   off    = (int*)alloc((size_t)NN * 4);
    int*   degw   = (int*)alloc((size_t)NN * 4);
    int*   csr_src= (int*)alloc((size_t)NBK * SLOT * 4);
    unsigned int* tmp = (unsigned int*)alloc((size_t)NBK * SLOT * 4);
    int*   gcur   = (int*)alloc((size_t)256 * 4);

    // --- prep (W transpose + cursors + permuted biases) & CSR build ---
    k_prep<<<129, 256, 0, stream>>>(W1, W2, b1, b2, Wt1, Wt2, b1p, b2p, gcur);
    k_bin2<<<400, 256, 0, stream>>>(row, col, gcur, tmp);
    k_bucket<<<NBK, 1024, 0, stream>>>(tmp, gcur, off, degw, dinv, csr_src);

    // --- layer 1 (f32 input, in-register bf16 pack; fp8 H) ---
    k_gemm<true><<<cdiv(NN, 128), 256, 0, stream>>>((const void*)x, Wt1, dinv, Hs8);
    k_agg<false><<<NN / 4, 256, 0, stream>>>((const uint2*)Hs8, off, degw, csr_src,
                                             dinv, b1p, (void*)A1b);
    // --- layer 2 ---
    k_gemm<false><<<cdiv(NN, 128), 256, 0, stream>>>((const void*)A1b, Wt2, dinv, Hs8);
    k_agg<true><<<NN / 4, 256, 0, stream>>>((const uint2*)Hs8, off, degw, csr_src,
                                            dinv, b2p, (void*)A2b);

    // --- fused mean pool + head ---
    k_poolhead<<<NG, 256, 0, stream>>>(A2b, batch, u, Wh1, bh1, Wh2, bh2, out);
}

// Round 16
// 277.770 us; speedup vs baseline: 1.0741x; 1.0464x over previous
//
#include <hip/hip_runtime.h>
#include <hip/hip_bf16.h>

#define NN 100000   // nodes
#define NE 1600000  // edges
#define NG 1000     // graphs
#define NBK 196     // dst buckets of 512 nodes (196*512 >= NN)
#define BSH 9       // bucket shift
#define SLOT 10240  // slack region per bucket (mean 8192 + 4-align padding)

typedef short short8 __attribute__((ext_vector_type(8)));
typedef float f32x4 __attribute__((ext_vector_type(4)));
typedef float f32x2 __attribute__((ext_vector_type(2)));

static inline int cdiv(int a, int b) { return (a + b - 1) / b; }

// f32 -> bf16 (RNE) and helpers
__device__ __forceinline__ unsigned short f2b(float f) {
    unsigned int u = __float_as_uint(f);
    u += 0x7fff + ((u >> 16) & 1);
    return (unsigned short)(u >> 16);
}
__device__ __forceinline__ unsigned int pack2(float lo, float hi) {
    return (unsigned int)f2b(lo) | ((unsigned int)f2b(hi) << 16);
}

// fp8 e4m3 (OCP) hardware converts; word select must be an immediate constant
template <int W>
__device__ __forceinline__ f32x2 f8_2f(unsigned int v) {
    return __builtin_amdgcn_cvt_pk_f32_fp8((int)v, W);
}
__device__ __forceinline__ unsigned int f2f8_lo(float a, float b, unsigned int old) {
    return (unsigned int)__builtin_amdgcn_cvt_pk_fp8_f32(a, b, (int)old, false);
}
__device__ __forceinline__ unsigned int f2f8_hi(float a, float b, unsigned int old) {
    return (unsigned int)__builtin_amdgcn_cvt_pk_fp8_f32(a, b, (int)old, true);
}

// ------------------------------------------------- prep: W transpose + cursors + permuted biases
// Permuted byte order for fp8 rows: byte q holds col (q&7)*16 + (q>>3).
__global__ __launch_bounds__(256) void k_prep(const float* __restrict__ W1,
                                              const float* __restrict__ W2,
                                              const float* __restrict__ b1,
                                              const float* __restrict__ b2,
                                              unsigned short* __restrict__ Wt1,
                                              unsigned short* __restrict__ Wt2,
                                              float* __restrict__ b1p,
                                              float* __restrict__ b2p,
                                              int* __restrict__ gcur) {
    int b = blockIdx.x, t = threadIdx.x;
    if (b < 128) {
        if (t < 128) Wt1[b * 128 + t] = f2b(W1[t * 128 + b]);
        else         Wt2[b * 128 + (t - 128)] = f2b(W2[(t - 128) * 128 + b]);
    } else {
        if (t < NBK) gcur[t] = t * SLOT;
        if (t < 128) {
            int c = (t & 7) * 16 + (t >> 3);  // col held at permuted position t
            b1p[t] = b1[c];
            b2p[t] = b2[c];
        }
    }
}

// -------------------------------------------------------- two-phase binning
// LDS-staged: phase 1 reads edges ONCE, stages packed entries + bucket ids in
// LDS; phase 2 scatters from LDS (kills the 12.8MB global re-read).
__global__ __launch_bounds__(256) void k_bin2(const int* __restrict__ row,
                                              const int* __restrict__ col,
                                              int* __restrict__ gcur,
                                              unsigned int* __restrict__ tmp) {
    __shared__ unsigned int ent[4000];
    __shared__ unsigned char bkt[4000];
    __shared__ int cnt[NBK];
    __shared__ int gbase[NBK];
    int t = threadIdx.x;
    if (t < NBK) cnt[t] = 0;
    __syncthreads();
    const int q0 = blockIdx.x * 1000;  // int4 index base (4000 edges)
    const int4* col4 = (const int4*)col;
    const int4* row4 = (const int4*)row;
#pragma unroll
    for (int it = 0; it < 4; it++) {
        int idx = it * 256 + t;
        if (idx < 1000) {
            int4 c = col4[q0 + idx];
            int4 r = row4[q0 + idx];
            int d, b;
            d = c.x; b = d >> BSH; atomicAdd(&cnt[b], 1);
            ent[idx * 4 + 0] = ((unsigned int)(d & 511) << 17) | (unsigned int)r.x;
            bkt[idx * 4 + 0] = (unsigned char)b;
            d = c.y; b = d >> BSH; atomicAdd(&cnt[b], 1);
            ent[idx * 4 + 1] = ((unsigned int)(d & 511) << 17) | (unsigned int)r.y;
            bkt[idx * 4 + 1] = (unsigned char)b;
            d = c.z; b = d >> BSH; atomicAdd(&cnt[b], 1);
            ent[idx * 4 + 2] = ((unsigned int)(d & 511) << 17) | (unsigned int)r.z;
            bkt[idx * 4 + 2] = (unsigned char)b;
            d = c.w; b = d >> BSH; atomicAdd(&cnt[b], 1);
            ent[idx * 4 + 3] = ((unsigned int)(d & 511) << 17) | (unsigned int)r.w;
            bkt[idx * 4 + 3] = (unsigned char)b;
        }
    }
    __syncthreads();
    if (t < NBK) {
        gbase[t] = atomicAdd(&gcur[t], cnt[t]);
        cnt[t] = 0;  // becomes local cursor
    }
    __syncthreads();
#pragma unroll
    for (int it = 0; it < 16; it++) {
        int i = it * 256 + t;  // 4096 slots; guard at 4000
        if (i < 4000) {
            int b = bkt[i];
            int p = atomicAdd(&cnt[b], 1);
            tmp[gbase[b] + p] = ent[i];
        }
    }
}

// -------------------------------------------------------- per-bucket CSR
// 1024 threads/block (R14-verified win): 196 blocks can't fill 256 CUs,
// so 16 waves/block hide latency; phase loops shorten 4x.
__global__ __launch_bounds__(1024) void k_bucket(const unsigned int* __restrict__ tmp,
                                                 const int* __restrict__ gcur,
                                                 int* __restrict__ off,
                                                 int* __restrict__ degw,
                                                 float* __restrict__ dinv,
                                                 int* __restrict__ csr_src) {
    __shared__ int cnt[512];
    __shared__ int loff[512];
    __shared__ int sh[256];
    int b = blockIdx.x, t = threadIdx.x;
    int j0 = b << BSH;
    int nd = min(512, NN - j0);
    int rb = b * SLOT;
    int m = gcur[b] - rb;
    if (t < 512) cnt[t] = 0;
    __syncthreads();
    for (int i = t; i < m; i += 1024)
        atomicAdd(&cnt[tmp[rb + i] >> 17], 1);
    __syncthreads();
    int r0 = 0, r1 = 0, p0 = 0, ts = 0;
    if (t < 256) {
        r0 = cnt[2 * t]; r1 = cnt[2 * t + 1];
        p0 = (r0 + 3) & ~3;
        int p1 = (r1 + 3) & ~3;  // pad to 4-entry alignment
        ts = p0 + p1;
        sh[t] = ts;
    }
    __syncthreads();
    for (int d = 1; d < 256; d <<= 1) {
        int u = (t >= d && t < 256) ? sh[t - d] : 0;
        __syncthreads();
        if (t < 256) sh[t] += u;
        __syncthreads();
    }
    if (t < 256) {
        int ex = sh[t] - ts;
        loff[2 * t] = ex;
        loff[2 * t + 1] = ex + p0;
    }
    __syncthreads();
    for (int j = t; j < nd; j += 1024) {
        int o = rb + loff[j];
        int dg = cnt[j];
        off[j0 + j] = o;
        degw[j0 + j] = dg;
        dinv[j0 + j] = rsqrtf((float)(dg + 1));  // +1 self-loop
        cnt[j] = o;  // becomes cursor
    }
    __syncthreads();
    for (int i = t; i < m; i += 1024) {
        unsigned int e = tmp[rb + i];
        int d = e >> 17;
        int s = (int)(e & 0x1FFFFu);
        int p = atomicAdd(&cnt[d], 1);
        csr_src[p] = s;
    }
}

// ---------------------------------------------------------------- MFMA GEMM
// Hs8[r] = fp8( dinv[r] * (A @ Wt^T) row r ), PERMUTED byte order (q=n16*8+ct).
template <bool AF32>
__global__ __launch_bounds__(256) void k_gemm(const void* __restrict__ Ap,
                                              const unsigned short* __restrict__ Wt,
                                              const float* __restrict__ dinv,
                                              unsigned char* __restrict__ Hs8) {
    __shared__ __align__(16) unsigned short Ws[128 * 128];  // 32 KB
    int t = threadIdx.x;
#pragma unroll
    for (int i = 0; i < 8; i++) {
        int id = t + i * 256;
        int n = id >> 4, c = id & 15;
        *(short8*)((char*)Ws + n * 256 + ((c ^ (n & 15)) << 4)) =
            *(const short8*)(Wt + n * 128 + c * 8);
    }
    __syncthreads();

    int lane = t & 63, wid = t >> 6;
    int n16 = lane & 15, quad = lane >> 4;
    int row_base = blockIdx.x * 128 + wid * 32;

    short8 a[2][4];
#pragma unroll
    for (int rt = 0; rt < 2; rt++) {
        int r = row_base + rt * 16 + n16;
        if (r > NN - 1) r = NN - 1;
        if (AF32) {
            const float* ap = (const float*)Ap + (size_t)r * 128 + quad * 8;
#pragma unroll
            for (int ks = 0; ks < 4; ks++) {
                float4 v0 = *(const float4*)(ap + ks * 32);
                float4 v1 = *(const float4*)(ap + ks * 32 + 4);
                uint4 up;
                up.x = pack2(v0.x, v0.y); up.y = pack2(v0.z, v0.w);
                up.z = pack2(v1.x, v1.y); up.w = pack2(v1.z, v1.w);
                a[rt][ks] = *(short8*)&up;
            }
        } else {
            const unsigned short* ap = (const unsigned short*)Ap + (size_t)r * 128 + quad * 8;
#pragma unroll
            for (int ks = 0; ks < 4; ks++)
                a[rt][ks] = *(const short8*)(ap + ks * 32);
        }
    }

    f32x4 acc[2][8];
#pragma unroll
    for (int rt = 0; rt < 2; rt++)
#pragma unroll
        for (int ct = 0; ct < 8; ct++)
            acc[rt][ct] = (f32x4){0.f, 0.f, 0.f, 0.f};

#pragma unroll
    for (int ks = 0; ks < 4; ks++) {
#pragma unroll
        for (int ct = 0; ct < 8; ct++) {
            short8 b = *(const short8*)((const char*)Ws +
                        (ct * 16 + n16) * 256 + ((((ks << 2) + quad) ^ n16) << 4));
            acc[0][ct] = __builtin_amdgcn_mfma_f32_16x16x32_bf16(a[0][ks], b, acc[0][ct], 0, 0, 0);
            acc[1][ct] = __builtin_amdgcn_mfma_f32_16x16x32_bf16(a[1][ks], b, acc[1][ct], 0, 0, 0);
        }
    }

    // epilogue: thread holds cols ct*16+n16 of row -> permuted bytes n16*8+ct
#pragma unroll
    for (int rt = 0; rt < 2; rt++) {
#pragma unroll
        for (int reg = 0; reg < 4; reg++) {
            int row = row_base + rt * 16 + quad * 4 + reg;
            if (row < NN) {
                float di = dinv[row];
                unsigned int u0 = 0, u1 = 0;
                u0 = f2f8_lo(acc[rt][0][reg] * di, acc[rt][1][reg] * di, u0);
                u0 = f2f8_hi(acc[rt][2][reg] * di, acc[rt][3][reg] * di, u0);
                u1 = f2f8_lo(acc[rt][4][reg] * di, acc[rt][5][reg] * di, u1);
                u1 = f2f8_hi(acc[rt][6][reg] * di, acc[rt][7][reg] * di, u1);
                uint2 o; o.x = u0; o.y = u1;
                ((uint2*)(Hs8 + (size_t)row * 128))[n16] = o;
            }
        }
    }
}

// ---------------------------------------------------------------- aggregation
// out[i] = relu( dinv[i] * (Hs[i] + sum_e Hs[src_e]) + bias )
// Single-round formulation: all indices (<=2 int4) loaded upfront, all <=8
// row-gathers issued together predicated on slot<deg (unselected rows stay 0;
// fp8 0x00 == +0.0 so unconditional unpack is exact). Rare deg>32 remainder
// falls back to the R12 loop. Gather shape (uint2/lane, 4x16) unchanged.
template <bool FP8OUT>
__global__ __launch_bounds__(256) void k_agg(const uint2* __restrict__ H2,
                                             const int* __restrict__ off,
                                             const int* __restrict__ degw,
                                             const int* __restrict__ csr_src,
                                             const float* __restrict__ dinv,
                                             const float* __restrict__ biasp,
                                             void* __restrict__ outp) {
    int node = blockIdx.x * 4 + (threadIdx.x >> 6);
    int lane = threadIdx.x & 63;
    int sub = lane >> 4, li = lane & 15;
    float2 A0 = {0.f, 0.f}, A1 = {0.f, 0.f}, A2 = {0.f, 0.f}, A3 = {0.f, 0.f};
    f32x2 p;
#define ACC8(V) { \
        p = f8_2f<0>((V).x); A0.x += p.x; A0.y += p.y; \
        p = f8_2f<1>((V).x); A1.x += p.x; A1.y += p.y; \
        p = f8_2f<0>((V).y); A2.x += p.x; A2.y += p.y; \
        p = f8_2f<1>((V).y); A3.x += p.x; A3.y += p.y; }
    int deg = degw[node];
    int base = off[node];
    int slot = sub * 4;
    // upfront: both index vectors + self row, then all gathers back-to-back
    int4 iA = *(const int4*)(csr_src + base + slot);
    int4 iB;
    bool hasB = deg > 16;
    if (hasB) iB = *(const int4*)(csr_src + base + 16 + slot);
    uint2 v = {0, 0};
    if (sub == 0) v = H2[(size_t)node * 16 + li];  // self (already dinv-scaled)
    uint2 w0 = {0,0}, w1 = {0,0}, w2 = {0,0}, w3 = {0,0};
    uint2 w4 = {0,0}, w5 = {0,0}, w6 = {0,0}, w7 = {0,0};
    if (slot + 0 < deg) w0 = H2[(size_t)iA.x * 16 + li];
    if (slot + 1 < deg) w1 = H2[(size_t)iA.y * 16 + li];
    if (slot + 2 < deg) w2 = H2[(size_t)iA.z * 16 + li];
    if (slot + 3 < deg) w3 = H2[(size_t)iA.w * 16 + li];
    if (hasB) {
        if (slot + 16 < deg) w4 = H2[(size_t)iB.x * 16 + li];
        if (slot + 17 < deg) w5 = H2[(size_t)iB.y * 16 + li];
        if (slot + 18 < deg) w6 = H2[(size_t)iB.z * 16 + li];
        if (slot + 19 < deg) w7 = H2[(size_t)iB.w * 16 + li];
    }
    ACC8(v)
    ACC8(w0) ACC8(w1) ACC8(w2) ACC8(w3)
    if (hasB) { ACC8(w4) ACC8(w5) ACC8(w6) ACC8(w7) }
    // rare remainder (deg > 32): old loop structure
    if (deg > 32) {
        int e = base + 32, e1 = base + deg;
        for (; e + 16 <= e1; e += 16) {
            int4 sv = *(const int4*)(csr_src + e + sub * 4);
            uint2 x0 = H2[(size_t)sv.x * 16 + li];
            uint2 x1 = H2[(size_t)sv.y * 16 + li];
            uint2 x2 = H2[(size_t)sv.z * 16 + li];
            uint2 x3 = H2[(size_t)sv.w * 16 + li];
            ACC8(x0) ACC8(x1) ACC8(x2) ACC8(x3)
        }
        for (; e + 8 <= e1; e += 8) {
            int2 sv = *(const int2*)(csr_src + e + sub * 2);
            uint2 xA = H2[(size_t)sv.x * 16 + li];
            uint2 xB = H2[(size_t)sv.y * 16 + li];
            ACC8(xA) ACC8(xB)
        }
        for (; e < e1; e += 4) {
            int ee = e + sub;
            if (ee < e1) {
                int s = csr_src[ee];
                uint2 w = H2[(size_t)s * 16 + li];
                ACC8(w)
            }
        }
    }
#undef ACC8
#pragma unroll
    for (int d = 16; d <= 32; d <<= 1) {
        A0.x += __shfl_xor(A0.x, d); A0.y += __shfl_xor(A0.y, d);
        A1.x += __shfl_xor(A1.x, d); A1.y += __shfl_xor(A1.y, d);
        A2.x += __shfl_xor(A2.x, d); A2.y += __shfl_xor(A2.y, d);
        A3.x += __shfl_xor(A3.x, d); A3.y += __shfl_xor(A3.y, d);
    }
    if (sub == 0) {
        float di = dinv[node];
        const float4* b4 = (const float4*)biasp;  // permuted bias
        float4 bA = b4[li * 2], bB = b4[li * 2 + 1];
        float r0 = fmaxf(fmaf(di, A0.x, bA.x), 0.f);  // col  0+li
        float r1 = fmaxf(fmaf(di, A0.y, bA.y), 0.f);  // col 16+li
        float r2 = fmaxf(fmaf(di, A1.x, bA.z), 0.f);
        float r3 = fmaxf(fmaf(di, A1.y, bA.w), 0.f);
        float r4 = fmaxf(fmaf(di, A2.x, bB.x), 0.f);
        float r5 = fmaxf(fmaf(di, A2.y, bB.y), 0.f);
        float r6 = fmaxf(fmaf(di, A3.x, bB.z), 0.f);
        float r7 = fmaxf(fmaf(di, A3.y, bB.w), 0.f);
        if (FP8OUT) {  // fp8 permuted (8B packed store)
            unsigned int u0 = 0, u1 = 0;
            u0 = f2f8_lo(r0, r1, u0); u0 = f2f8_hi(r2, r3, u0);
            u1 = f2f8_lo(r4, r5, u1); u1 = f2f8_hi(r6, r7, u1);
            uint2 o; o.x = u0; o.y = u1;
            ((uint2*)outp)[(size_t)node * 16 + li] = o;
        } else {  // bf16 natural (for GEMM2 A-frags)
            unsigned short* ob = (unsigned short*)outp + (size_t)node * 128 + li;
            ob[0]   = f2b(r0); ob[16]  = f2b(r1); ob[32]  = f2b(r2); ob[48]  = f2b(r3);
            ob[64]  = f2b(r4); ob[80]  = f2b(r5); ob[96]  = f2b(r6); ob[112] = f2b(r7);
        }
    }
}

// ------------------------------------------------- fused mean-pool + head MLP
// A2: fp8 permuted. part[] indexed by permuted byte q; hc[] unpermutes.
__global__ __launch_bounds__(256) void k_poolhead(const unsigned char* __restrict__ A,
                                                  const int* __restrict__ batch,
                                                  const float* __restrict__ u,
                                                  const float* __restrict__ Wh1,
                                                  const float* __restrict__ bh1,
                                                  const float* __restrict__ Wh2,
                                                  const float* __restrict__ bh2,
                                                  float* __restrict__ out) {
    int g = blockIdx.x, t = threadIdx.x;
    int lo = 0, hi = NN;
    while (lo < hi) { int m = (lo + hi) >> 1; if (batch[m] < g) lo = m + 1; else hi = m; }
    int start = lo;
    hi = NN;
    while (lo < hi) { int m = (lo + hi) >> 1; if (batch[m] < g + 1) lo = m + 1; else hi = m; }
    int end = lo;

    int li = t & 7;    // 16-byte chunk of the 128B row
    int ri = t >> 3;   // row offset 0..31
    float acc[16];
#pragma unroll
    for (int j = 0; j < 16; j++) acc[j] = 0.f;
    f32x2 p;
    for (int i = start + ri; i < end; i += 32) {
        uint4 v = ((const uint4*)A)[(size_t)i * 8 + li];
#define UP(VV, base) p = f8_2f<0>(VV); acc[base] += p.x; acc[base+1] += p.y; \
                     p = f8_2f<1>(VV); acc[base+2] += p.x; acc[base+3] += p.y;
        UP(v.x, 0) UP(v.y, 4) UP(v.z, 8) UP(v.w, 12)
#undef UP
    }
#pragma unroll
    for (int j = 0; j < 16; j++) {
        acc[j] += __shfl_xor(acc[j], 8);
        acc[j] += __shfl_xor(acc[j], 16);
        acc[j] += __shfl_xor(acc[j], 32);
    }
    __shared__ float part[4][128];
    __shared__ float hc[192];
    __shared__ float tt[128];
    int w = t >> 6;
    if ((t & 63) < 8) {
#pragma unroll
        for (int j = 0; j < 16; j++) part[w][li * 16 + j] = acc[j];  // index = byte q
    }
    __syncthreads();
    float cntf = (float)max(end - start, 1);
    if (t < 128) {
        int q = (t & 15) * 8 + (t >> 4);  // permuted position of col t
        hc[t] = (part[0][q] + part[1][q] + part[2][q] + part[3][q]) / cntf;
    } else if (t < 192) {
        hc[t] = u[g * 64 + (t - 128)];
    }
    __syncthreads();
    if (t < 128) {
        float a2 = bh1[t];
        for (int k = 0; k < 192; k++) a2 = fmaf(hc[k], Wh1[k * 128 + t], a2);
        tt[t] = fmaxf(a2, 0.f);
    }
    __syncthreads();
    if (t < 2) {
        float o = bh2[t];
        for (int c2 = 0; c2 < 128; c2++) o = fmaf(tt[c2], Wh2[c2 * 2 + t], o);
        out[g * 2 + t] = o;
    }
}

// ---------------------------------------------------------------- launcher
extern "C" void kernel_launch(void* const* d_in, const int* in_sizes, int n_in,
                              void* d_out, int out_size, void* d_ws, size_t ws_size,
                              hipStream_t stream) {
    const float* x   = (const float*)d_in[0];
    const int*   ei  = (const int*)d_in[1];
    const int*   row = ei;        // edge_index[0] = src
    const int*   col = ei + NE;   // edge_index[1] = dst
    const float* u   = (const float*)d_in[2];
    const int*   batch = (const int*)d_in[3];
    const float* W1  = (const float*)d_in[5];
    const float* b1  = (const float*)d_in[6];
    const float* W2  = (const float*)d_in[7];
    const float* b2  = (const float*)d_in[8];
    const float* Wh1 = (const float*)d_in[9];
    const float* bh1 = (const float*)d_in[10];
    const float* Wh2 = (const float*)d_in[11];
    const float* bh2 = (const float*)d_in[12];
    float* out = (float*)d_out;

    char* ws = (char*)d_ws;
    size_t o = 0;
    auto alloc = [&](size_t bytes) -> void* {
        void* p = ws + o;
        o += (bytes + 511) & ~(size_t)511;
        return p;
    };
    unsigned char*  Hs8 = (unsigned char*)alloc((size_t)NN * 128);       // fp8 permuted
    unsigned short* A1b = (unsigned short*)alloc((size_t)NN * 128 * 2);  // bf16 natural
    unsigned char*  A2b = (unsigned char*)alloc((size_t)NN * 128);       // fp8 permuted
    unsigned short* Wt1 = (unsigned short*)alloc((size_t)128 * 128 * 2);
    unsigned short* Wt2 = (unsigned short*)alloc((size_t)128 * 128 * 2);
    float* b1p    = (float*)alloc((size_t)128 * 4);
    float* b2p    = (float*)alloc((size_t)128 * 4);
    float* dinv   = (float*)alloc((size_t)NN * 4);
    int*   off    = (int*)alloc((size_t)NN * 4);
    int*   degw   = (int*)alloc((size_t)NN * 4);
    int*   csr_src= (int*)alloc((size_t)NBK * SLOT * 4 + 256);  // +slack for predicated overread
    unsigned int* tmp = (unsigned int*)alloc((size_t)NBK * SLOT * 4);
    int*   gcur   = (int*)alloc((size_t)256 * 4);

    // --- prep (W transpose + cursors + permuted biases) & CSR build ---
    k_prep<<<129, 256, 0, stream>>>(W1, W2, b1, b2, Wt1, Wt2, b1p, b2p, gcur);
    k_bin2<<<400, 256, 0, stream>>>(row, col, gcur, tmp);
    k_bucket<<<NBK, 1024, 0, stream>>>(tmp, gcur, off, degw, dinv, csr_src);

    // --- layer 1 (f32 input, in-register bf16 pack; fp8 H) ---
    k_gemm<true><<<cdiv(NN, 128), 256, 0, stream>>>((const void*)x, Wt1, dinv, Hs8);
    k_agg<false><<<NN / 4, 256, 0, stream>>>((const uint2*)Hs8, off, degw, csr_src,
                                             dinv, b1p, (void*)A1b);
    // --- layer 2 ---
    k_gemm<false><<<cdiv(NN, 128), 256, 0, stream>>>((const void*)A1b, Wt2, dinv, Hs8);
    k_agg<true><<<NN / 4, 256, 0, stream>>>((const uint2*)Hs8, off, degw, csr_src,
                                            dinv, b2p, (void*)A2b);

    // --- fused mean pool + head ---
    k_poolhead<<<NG, 256, 0, stream>>>(A2b, batch, u, Wh1, bh1, Wh2, bh2, out);
}

// Round 17
// 269.748 us; speedup vs baseline: 1.1060x; 1.0297x over previous
//
#include <hip/hip_runtime.h>
#include <hip/hip_bf16.h>

#define NN 100000   // nodes
#define NE 1600000  // edges
#define NG 1000     // graphs
#define NBK 196     // dst buckets of 512 nodes (196*512 >= NN)
#define BSH 9       // bucket shift
#define SLOT 10240  // slack region per bucket (mean 8192 + 4-align padding)

typedef short short8 __attribute__((ext_vector_type(8)));
typedef float f32x4 __attribute__((ext_vector_type(4)));
typedef float f32x2 __attribute__((ext_vector_type(2)));

static inline int cdiv(int a, int b) { return (a + b - 1) / b; }

// f32 -> bf16 (RNE) and helpers
__device__ __forceinline__ unsigned short f2b(float f) {
    unsigned int u = __float_as_uint(f);
    u += 0x7fff + ((u >> 16) & 1);
    return (unsigned short)(u >> 16);
}
__device__ __forceinline__ unsigned int pack2(float lo, float hi) {
    return (unsigned int)f2b(lo) | ((unsigned int)f2b(hi) << 16);
}

// fp8 e4m3 (OCP) hardware converts; word select must be an immediate constant
template <int W>
__device__ __forceinline__ f32x2 f8_2f(unsigned int v) {
    return __builtin_amdgcn_cvt_pk_f32_fp8((int)v, W);
}
__device__ __forceinline__ unsigned int f2f8_lo(float a, float b, unsigned int old) {
    return (unsigned int)__builtin_amdgcn_cvt_pk_fp8_f32(a, b, (int)old, false);
}
__device__ __forceinline__ unsigned int f2f8_hi(float a, float b, unsigned int old) {
    return (unsigned int)__builtin_amdgcn_cvt_pk_fp8_f32(a, b, (int)old, true);
}

// ------------------------------------------------- prep: W transpose + cursors + permuted biases
// Permuted byte order for fp8 rows: byte q holds col (q&7)*16 + (q>>3).
__global__ __launch_bounds__(256) void k_prep(const float* __restrict__ W1,
                                              const float* __restrict__ W2,
                                              const float* __restrict__ b1,
                                              const float* __restrict__ b2,
                                              unsigned short* __restrict__ Wt1,
                                              unsigned short* __restrict__ Wt2,
                                              float* __restrict__ b1p,
                                              float* __restrict__ b2p,
                                              int* __restrict__ gcur) {
    int b = blockIdx.x, t = threadIdx.x;
    if (b < 128) {
        if (t < 128) Wt1[b * 128 + t] = f2b(W1[t * 128 + b]);
        else         Wt2[b * 128 + (t - 128)] = f2b(W2[(t - 128) * 128 + b]);
    } else {
        if (t < NBK) gcur[t] = t * SLOT;
        if (t < 128) {
            int c = (t & 7) * 16 + (t >> 3);  // col held at permuted position t
            b1p[t] = b1[c];
            b2p[t] = b2[c];
        }
    }
}

// -------------------------------------------------------- two-phase binning
// LDS counting-sort: entries sorted into bucket order in LDS, then written out
// linearly -> consecutive lanes in a bucket run hit consecutive global
// addresses (coalesced), replacing 4000 scattered 4B stores per block.
__global__ __launch_bounds__(256) void k_bin2(const int* __restrict__ row,
                                              const int* __restrict__ col,
                                              int* __restrict__ gcur,
                                              unsigned int* __restrict__ tmp) {
    __shared__ unsigned int ent[4000];
    __shared__ unsigned int srt[4000];
    __shared__ unsigned char bkt[4000];
    __shared__ unsigned char bky[4000];
    __shared__ int cnt[NBK];
    __shared__ int gbase[NBK];
    __shared__ int lbase[NBK];
    __shared__ int sh[256];
    int t = threadIdx.x;
    if (t < NBK) cnt[t] = 0;
    __syncthreads();
    const int q0 = blockIdx.x * 1000;  // int4 index base (4000 edges)
    const int4* col4 = (const int4*)col;
    const int4* row4 = (const int4*)row;
#pragma unroll
    for (int it = 0; it < 4; it++) {
        int idx = it * 256 + t;
        if (idx < 1000) {
            int4 c = col4[q0 + idx];
            int4 r = row4[q0 + idx];
            int d, b;
            d = c.x; b = d >> BSH; atomicAdd(&cnt[b], 1);
            ent[idx * 4 + 0] = ((unsigned int)(d & 511) << 17) | (unsigned int)r.x;
            bkt[idx * 4 + 0] = (unsigned char)b;
            d = c.y; b = d >> BSH; atomicAdd(&cnt[b], 1);
            ent[idx * 4 + 1] = ((unsigned int)(d & 511) << 17) | (unsigned int)r.y;
            bkt[idx * 4 + 1] = (unsigned char)b;
            d = c.z; b = d >> BSH; atomicAdd(&cnt[b], 1);
            ent[idx * 4 + 2] = ((unsigned int)(d & 511) << 17) | (unsigned int)r.z;
            bkt[idx * 4 + 2] = (unsigned char)b;
            d = c.w; b = d >> BSH; atomicAdd(&cnt[b], 1);
            ent[idx * 4 + 3] = ((unsigned int)(d & 511) << 17) | (unsigned int)r.w;
            bkt[idx * 4 + 3] = (unsigned char)b;
        }
    }
    __syncthreads();
    // local exclusive scan of cnt -> lbase; reserve global runs
    int v = (t < NBK) ? cnt[t] : 0;
    sh[t] = v;
    __syncthreads();
    for (int d = 1; d < 256; d <<= 1) {
        int u = (t >= d) ? sh[t - d] : 0;
        __syncthreads();
        sh[t] += u;
        __syncthreads();
    }
    if (t < NBK) {
        lbase[t] = sh[t] - v;
        gbase[t] = atomicAdd(&gcur[t], v);
        cnt[t] = sh[t] - v;  // becomes local cursor
    }
    __syncthreads();
    // scatter into bucket-sorted LDS order (LDS atomics: cheap)
#pragma unroll
    for (int it = 0; it < 16; it++) {
        int i = it * 256 + t;
        if (i < 4000) {
            int b = bkt[i];
            int p = atomicAdd(&cnt[b], 1);
            srt[p] = ent[i];
            bky[p] = (unsigned char)b;
        }
    }
    __syncthreads();
    // coalesced write-out: consecutive slots in a run -> consecutive addresses
#pragma unroll
    for (int it = 0; it < 16; it++) {
        int i = it * 256 + t;
        if (i < 4000) {
            int b = bky[i];
            tmp[gbase[b] + (i - lbase[b])] = srt[i];
        }
    }
}

// -------------------------------------------------------- per-bucket CSR
// 1024 threads/block (R14-verified win): 196 blocks can't fill 256 CUs,
// so 16 waves/block hide latency; phase loops shorten 4x.
__global__ __launch_bounds__(1024) void k_bucket(const unsigned int* __restrict__ tmp,
                                                 const int* __restrict__ gcur,
                                                 int* __restrict__ off,
                                                 int* __restrict__ degw,
                                                 float* __restrict__ dinv,
                                                 int* __restrict__ csr_src) {
    __shared__ int cnt[512];
    __shared__ int loff[512];
    __shared__ int sh[256];
    int b = blockIdx.x, t = threadIdx.x;
    int j0 = b << BSH;
    int nd = min(512, NN - j0);
    int rb = b * SLOT;
    int m = gcur[b] - rb;
    if (t < 512) cnt[t] = 0;
    __syncthreads();
    for (int i = t; i < m; i += 1024)
        atomicAdd(&cnt[tmp[rb + i] >> 17], 1);
    __syncthreads();
    int r0 = 0, r1 = 0, p0 = 0, ts = 0;
    if (t < 256) {
        r0 = cnt[2 * t]; r1 = cnt[2 * t + 1];
        p0 = (r0 + 3) & ~3;
        int p1 = (r1 + 3) & ~3;  // pad to 4-entry alignment
        ts = p0 + p1;
        sh[t] = ts;
    }
    __syncthreads();
    for (int d = 1; d < 256; d <<= 1) {
        int u = (t >= d && t < 256) ? sh[t - d] : 0;
        __syncthreads();
        if (t < 256) sh[t] += u;
        __syncthreads();
    }
    if (t < 256) {
        int ex = sh[t] - ts;
        loff[2 * t] = ex;
        loff[2 * t + 1] = ex + p0;
    }
    __syncthreads();
    for (int j = t; j < nd; j += 1024) {
        int o = rb + loff[j];
        int dg = cnt[j];
        off[j0 + j] = o;
        degw[j0 + j] = dg;
        dinv[j0 + j] = rsqrtf((float)(dg + 1));  // +1 self-loop
        cnt[j] = o;  // becomes cursor
    }
    __syncthreads();
    for (int i = t; i < m; i += 1024) {
        unsigned int e = tmp[rb + i];
        int d = e >> 17;
        int s = (int)(e & 0x1FFFFu);
        int p = atomicAdd(&cnt[d], 1);
        csr_src[p] = s;
    }
}

// ---------------------------------------------------------------- MFMA GEMM
// Hs8[r] = fp8( dinv[r] * (A @ Wt^T) row r ), PERMUTED byte order (q=n16*8+ct).
template <bool AF32>
__global__ __launch_bounds__(256) void k_gemm(const void* __restrict__ Ap,
                                              const unsigned short* __restrict__ Wt,
                                              const float* __restrict__ dinv,
                                              unsigned char* __restrict__ Hs8) {
    __shared__ __align__(16) unsigned short Ws[128 * 128];  // 32 KB
    int t = threadIdx.x;
#pragma unroll
    for (int i = 0; i < 8; i++) {
        int id = t + i * 256;
        int n = id >> 4, c = id & 15;
        *(short8*)((char*)Ws + n * 256 + ((c ^ (n & 15)) << 4)) =
            *(const short8*)(Wt + n * 128 + c * 8);
    }
    __syncthreads();

    int lane = t & 63, wid = t >> 6;
    int n16 = lane & 15, quad = lane >> 4;
    int row_base = blockIdx.x * 128 + wid * 32;

    short8 a[2][4];
#pragma unroll
    for (int rt = 0; rt < 2; rt++) {
        int r = row_base + rt * 16 + n16;
        if (r > NN - 1) r = NN - 1;
        if (AF32) {
            const float* ap = (const float*)Ap + (size_t)r * 128 + quad * 8;
#pragma unroll
            for (int ks = 0; ks < 4; ks++) {
                float4 v0 = *(const float4*)(ap + ks * 32);
                float4 v1 = *(const float4*)(ap + ks * 32 + 4);
                uint4 up;
                up.x = pack2(v0.x, v0.y); up.y = pack2(v0.z, v0.w);
                up.z = pack2(v1.x, v1.y); up.w = pack2(v1.z, v1.w);
                a[rt][ks] = *(short8*)&up;
            }
        } else {
            const unsigned short* ap = (const unsigned short*)Ap + (size_t)r * 128 + quad * 8;
#pragma unroll
            for (int ks = 0; ks < 4; ks++)
                a[rt][ks] = *(const short8*)(ap + ks * 32);
        }
    }

    f32x4 acc[2][8];
#pragma unroll
    for (int rt = 0; rt < 2; rt++)
#pragma unroll
        for (int ct = 0; ct < 8; ct++)
            acc[rt][ct] = (f32x4){0.f, 0.f, 0.f, 0.f};

#pragma unroll
    for (int ks = 0; ks < 4; ks++) {
#pragma unroll
        for (int ct = 0; ct < 8; ct++) {
            short8 b = *(const short8*)((const char*)Ws +
                        (ct * 16 + n16) * 256 + ((((ks << 2) + quad) ^ n16) << 4));
            acc[0][ct] = __builtin_amdgcn_mfma_f32_16x16x32_bf16(a[0][ks], b, acc[0][ct], 0, 0, 0);
            acc[1][ct] = __builtin_amdgcn_mfma_f32_16x16x32_bf16(a[1][ks], b, acc[1][ct], 0, 0, 0);
        }
    }

    // epilogue: thread holds cols ct*16+n16 of row -> permuted bytes n16*8+ct
#pragma unroll
    for (int rt = 0; rt < 2; rt++) {
#pragma unroll
        for (int reg = 0; reg < 4; reg++) {
            int row = row_base + rt * 16 + quad * 4 + reg;
            if (row < NN) {
                float di = dinv[row];
                unsigned int u0 = 0, u1 = 0;
                u0 = f2f8_lo(acc[rt][0][reg] * di, acc[rt][1][reg] * di, u0);
                u0 = f2f8_hi(acc[rt][2][reg] * di, acc[rt][3][reg] * di, u0);
                u1 = f2f8_lo(acc[rt][4][reg] * di, acc[rt][5][reg] * di, u1);
                u1 = f2f8_hi(acc[rt][6][reg] * di, acc[rt][7][reg] * di, u1);
                uint2 o; o.x = u0; o.y = u1;
                ((uint2*)(Hs8 + (size_t)row * 128))[n16] = o;
            }
        }
    }
}

// ---------------------------------------------------------------- aggregation
// out[i] = relu( dinv[i] * (Hs[i] + sum_e Hs[src_e]) + bias )
// Single-round predicated gather (R16-verified) + 32-bit byte-offset
// addressing (H is 12.8MB; forces s[base]+voffset load form, cutting the
// 64-bit address chain per gather).
template <bool FP8OUT>
__global__ __launch_bounds__(256) void k_agg(const unsigned char* __restrict__ Hb,
                                             const int* __restrict__ off,
                                             const int* __restrict__ degw,
                                             const int* __restrict__ csr_src,
                                             const float* __restrict__ dinv,
                                             const float* __restrict__ biasp,
                                             void* __restrict__ outp) {
    int node = blockIdx.x * 4 + (threadIdx.x >> 6);
    int lane = threadIdx.x & 63;
    int sub = lane >> 4, li = lane & 15;
    unsigned loff = (unsigned)li * 8u;
    float2 A0 = {0.f, 0.f}, A1 = {0.f, 0.f}, A2 = {0.f, 0.f}, A3 = {0.f, 0.f};
    f32x2 p;
#define LDH(idx) (*(const uint2*)(Hb + (unsigned)(idx) * 128u + loff))
#define ACC8(V) { \
        p = f8_2f<0>((V).x); A0.x += p.x; A0.y += p.y; \
        p = f8_2f<1>((V).x); A1.x += p.x; A1.y += p.y; \
        p = f8_2f<0>((V).y); A2.x += p.x; A2.y += p.y; \
        p = f8_2f<1>((V).y); A3.x += p.x; A3.y += p.y; }
    int deg = degw[node];
    int base = off[node];
    int slot = sub * 4;
    // upfront: both index vectors + self row, then all gathers back-to-back
    int4 iA = *(const int4*)(csr_src + base + slot);
    int4 iB;
    bool hasB = deg > 16;
    if (hasB) iB = *(const int4*)(csr_src + base + 16 + slot);
    uint2 v = {0, 0};
    if (sub == 0) v = LDH(node);  // self (already dinv-scaled)
    uint2 w0 = {0,0}, w1 = {0,0}, w2 = {0,0}, w3 = {0,0};
    uint2 w4 = {0,0}, w5 = {0,0}, w6 = {0,0}, w7 = {0,0};
    if (slot + 0 < deg) w0 = LDH(iA.x);
    if (slot + 1 < deg) w1 = LDH(iA.y);
    if (slot + 2 < deg) w2 = LDH(iA.z);
    if (slot + 3 < deg) w3 = LDH(iA.w);
    if (hasB) {
        if (slot + 16 < deg) w4 = LDH(iB.x);
        if (slot + 17 < deg) w5 = LDH(iB.y);
        if (slot + 18 < deg) w6 = LDH(iB.z);
        if (slot + 19 < deg) w7 = LDH(iB.w);
    }
    ACC8(v)
    ACC8(w0) ACC8(w1) ACC8(w2) ACC8(w3)
    if (hasB) { ACC8(w4) ACC8(w5) ACC8(w6) ACC8(w7) }
    // rare remainder (deg > 32)
    if (deg > 32) {
        int e = base + 32, e1 = base + deg;
        for (; e + 16 <= e1; e += 16) {
            int4 sv = *(const int4*)(csr_src + e + sub * 4);
            uint2 x0 = LDH(sv.x);
            uint2 x1 = LDH(sv.y);
            uint2 x2 = LDH(sv.z);
            uint2 x3 = LDH(sv.w);
            ACC8(x0) ACC8(x1) ACC8(x2) ACC8(x3)
        }
        for (; e + 8 <= e1; e += 8) {
            int2 sv = *(const int2*)(csr_src + e + sub * 2);
            uint2 xA = LDH(sv.x);
            uint2 xB = LDH(sv.y);
            ACC8(xA) ACC8(xB)
        }
        for (; e < e1; e += 4) {
            int ee = e + sub;
            if (ee < e1) {
                uint2 w = LDH(csr_src[ee]);
                ACC8(w)
            }
        }
    }
#undef ACC8
#undef LDH
#pragma unroll
    for (int d = 16; d <= 32; d <<= 1) {
        A0.x += __shfl_xor(A0.x, d); A0.y += __shfl_xor(A0.y, d);
        A1.x += __shfl_xor(A1.x, d); A1.y += __shfl_xor(A1.y, d);
        A2.x += __shfl_xor(A2.x, d); A2.y += __shfl_xor(A2.y, d);
        A3.x += __shfl_xor(A3.x, d); A3.y += __shfl_xor(A3.y, d);
    }
    if (sub == 0) {
        float di = dinv[node];
        const float4* b4 = (const float4*)biasp;  // permuted bias
        float4 bA = b4[li * 2], bB = b4[li * 2 + 1];
        float r0 = fmaxf(fmaf(di, A0.x, bA.x), 0.f);  // col  0+li
        float r1 = fmaxf(fmaf(di, A0.y, bA.y), 0.f);  // col 16+li
        float r2 = fmaxf(fmaf(di, A1.x, bA.z), 0.f);
        float r3 = fmaxf(fmaf(di, A1.y, bA.w), 0.f);
        float r4 = fmaxf(fmaf(di, A2.x, bB.x), 0.f);
        float r5 = fmaxf(fmaf(di, A2.y, bB.y), 0.f);
        float r6 = fmaxf(fmaf(di, A3.x, bB.z), 0.f);
        float r7 = fmaxf(fmaf(di, A3.y, bB.w), 0.f);
        if (FP8OUT) {  // fp8 permuted (8B packed store)
            unsigned int u0 = 0, u1 = 0;
            u0 = f2f8_lo(r0, r1, u0); u0 = f2f8_hi(r2, r3, u0);
            u1 = f2f8_lo(r4, r5, u1); u1 = f2f8_hi(r6, r7, u1);
            uint2 o; o.x = u0; o.y = u1;
            *(uint2*)((unsigned char*)outp + (unsigned)node * 128u + loff) = o;
        } else {  // bf16 natural (for GEMM2 A-frags)
            unsigned short* ob = (unsigned short*)outp + (size_t)node * 128 + li;
            ob[0]   = f2b(r0); ob[16]  = f2b(r1); ob[32]  = f2b(r2); ob[48]  = f2b(r3);
            ob[64]  = f2b(r4); ob[80]  = f2b(r5); ob[96]  = f2b(r6); ob[112] = f2b(r7);
        }
    }
}

// ------------------------------------------------- fused mean-pool + head MLP
// A2: fp8 permuted. part[] indexed by permuted byte q; hc[] unpermutes.
__global__ __launch_bounds__(256) void k_poolhead(const unsigned char* __restrict__ A,
                                                  const int* __restrict__ batch,
                                                  const float* __restrict__ u,
                                                  const float* __restrict__ Wh1,
                                                  const float* __restrict__ bh1,
                                                  const float* __restrict__ Wh2,
                                                  const float* __restrict__ bh2,
                                                  float* __restrict__ out) {
    int g = blockIdx.x, t = threadIdx.x;
    int lo = 0, hi = NN;
    while (lo < hi) { int m = (lo + hi) >> 1; if (batch[m] < g) lo = m + 1; else hi = m; }
    int start = lo;
    hi = NN;
    while (lo < hi) { int m = (lo + hi) >> 1; if (batch[m] < g + 1) lo = m + 1; else hi = m; }
    int end = lo;

    int li = t & 7;    // 16-byte chunk of the 128B row
    int ri = t >> 3;   // row offset 0..31
    float acc[16];
#pragma unroll
    for (int j = 0; j < 16; j++) acc[j] = 0.f;
    f32x2 p;
    for (int i = start + ri; i < end; i += 32) {
        uint4 v = ((const uint4*)A)[(size_t)i * 8 + li];
#define UP(VV, base) p = f8_2f<0>(VV); acc[base] += p.x; acc[base+1] += p.y; \
                     p = f8_2f<1>(VV); acc[base+2] += p.x; acc[base+3] += p.y;
        UP(v.x, 0) UP(v.y, 4) UP(v.z, 8) UP(v.w, 12)
#undef UP
    }
#pragma unroll
    for (int j = 0; j < 16; j++) {
        acc[j] += __shfl_xor(acc[j], 8);
        acc[j] += __shfl_xor(acc[j], 16);
        acc[j] += __shfl_xor(acc[j], 32);
    }
    __shared__ float part[4][128];
    __shared__ float hc[192];
    __shared__ float tt[128];
    int w = t >> 6;
    if ((t & 63) < 8) {
#pragma unroll
        for (int j = 0; j < 16; j++) part[w][li * 16 + j] = acc[j];  // index = byte q
    }
    __syncthreads();
    float cntf = (float)max(end - start, 1);
    if (t < 128) {
        int q = (t & 15) * 8 + (t >> 4);  // permuted position of col t
        hc[t] = (part[0][q] + part[1][q] + part[2][q] + part[3][q]) / cntf;
    } else if (t < 192) {
        hc[t] = u[g * 64 + (t - 128)];
    }
    __syncthreads();
    if (t < 128) {
        float a2 = bh1[t];
        for (int k = 0; k < 192; k++) a2 = fmaf(hc[k], Wh1[k * 128 + t], a2);
        tt[t] = fmaxf(a2, 0.f);
    }
    __syncthreads();
    if (t < 2) {
        float o = bh2[t];
        for (int c2 = 0; c2 < 128; c2++) o = fmaf(tt[c2], Wh2[c2 * 2 + t], o);
        out[g * 2 + t] = o;
    }
}

// ---------------------------------------------------------------- launcher
extern "C" void kernel_launch(void* const* d_in, const int* in_sizes, int n_in,
                              void* d_out, int out_size, void* d_ws, size_t ws_size,
                              hipStream_t stream) {
    const float* x   = (const float*)d_in[0];
    const int*   ei  = (const int*)d_in[1];
    const int*   row = ei;        // edge_index[0] = src
    const int*   col = ei + NE;   // edge_index[1] = dst
    const float* u   = (const float*)d_in[2];
    const int*   batch = (const int*)d_in[3];
    const float* W1  = (const float*)d_in[5];
    const float* b1  = (const float*)d_in[6];
    const float* W2  = (const float*)d_in[7];
    const float* b2  = (const float*)d_in[8];
    const float* Wh1 = (const float*)d_in[9];
    const float* bh1 = (const float*)d_in[10];
    const float* Wh2 = (const float*)d_in[11];
    const float* bh2 = (const float*)d_in[12];
    float* out = (float*)d_out;

    char* ws = (char*)d_ws;
    size_t o = 0;
    auto alloc = [&](size_t bytes) -> void* {
        void* p = ws + o;
        o += (bytes + 511) & ~(size_t)511;
        return p;
    };
    unsigned char*  Hs8 = (unsigned char*)alloc((size_t)NN * 128);       // fp8 permuted
    unsigned short* A1b = (unsigned short*)alloc((size_t)NN * 128 * 2);  // bf16 natural
    unsigned char*  A2b = (unsigned char*)alloc((size_t)NN * 128);       // fp8 permuted
    unsigned short* Wt1 = (unsigned short*)alloc((size_t)128 * 128 * 2);
    unsigned short* Wt2 = (unsigned short*)alloc((size_t)128 * 128 * 2);
    float* b1p    = (float*)alloc((size_t)128 * 4);
    float* b2p    = (float*)alloc((size_t)128 * 4);
    float* dinv   = (float*)alloc((size_t)NN * 4);
    int*   off    = (int*)alloc((size_t)NN * 4);
    int*   degw   = (int*)alloc((size_t)NN * 4);
    int*   csr_src= (int*)alloc((size_t)NBK * SLOT * 4 + 256);  // +slack for predicated overread
    unsigned int* tmp = (unsigned int*)alloc((size_t)NBK * SLOT * 4);
    int*   gcur   = (int*)alloc((size_t)256 * 4);

    // --- prep (W transpose + cursors + permuted biases) & CSR build ---
    k_prep<<<129, 256, 0, stream>>>(W1, W2, b1, b2, Wt1, Wt2, b1p, b2p, gcur);
    k_bin2<<<400, 256, 0, stream>>>(row, col, gcur, tmp);
    k_bucket<<<NBK, 1024, 0, stream>>>(tmp, gcur, off, degw, dinv, csr_src);

    // --- layer 1 (f32 input, in-register bf16 pack; fp8 H) ---
    k_gemm<true><<<cdiv(NN, 128), 256, 0, stream>>>((const void*)x, Wt1, dinv, Hs8);
    k_agg<false><<<NN / 4, 256, 0, stream>>>(Hs8, off, degw, csr_src,
                                             dinv, b1p, (void*)A1b);
    // --- layer 2 ---
    k_gemm<false><<<cdiv(NN, 128), 256, 0, stream>>>((const void*)A1b, Wt2, dinv, Hs8);
    k_agg<true><<<NN / 4, 256, 0, stream>>>(Hs8, off, degw, csr_src,
                                            dinv, b2p, (void*)A2b);

    // --- fused mean pool + head ---
    k_poolhead<<<NG, 256, 0, stream>>>(A2b, batch, u, Wh1, bh1, Wh2, bh2, out);
}

// Round 18
// 267.621 us; speedup vs baseline: 1.1148x; 1.0079x over previous
//
#include <hip/hip_runtime.h>
#include <hip/hip_bf16.h>

#define NN 100000   // nodes
#define NE 1600000  // edges
#define NG 1000     // graphs
#define NBK 196     // dst buckets of 512 nodes (196*512 >= NN)
#define BSH 9       // bucket shift
#define SLOT 10240  // slack region per bucket (mean 8192 + 4-align padding)

typedef short short8 __attribute__((ext_vector_type(8)));
typedef float f32x4 __attribute__((ext_vector_type(4)));
typedef float f32x2 __attribute__((ext_vector_type(2)));

static inline int cdiv(int a, int b) { return (a + b - 1) / b; }

// f32 -> bf16 (RNE) and helpers
__device__ __forceinline__ unsigned short f2b(float f) {
    unsigned int u = __float_as_uint(f);
    u += 0x7fff + ((u >> 16) & 1);
    return (unsigned short)(u >> 16);
}
__device__ __forceinline__ unsigned int pack2(float lo, float hi) {
    return (unsigned int)f2b(lo) | ((unsigned int)f2b(hi) << 16);
}

// fp8 e4m3 (OCP) hardware converts; word select must be an immediate constant
template <int W>
__device__ __forceinline__ f32x2 f8_2f(unsigned int v) {
    return __builtin_amdgcn_cvt_pk_f32_fp8((int)v, W);
}
__device__ __forceinline__ unsigned int f2f8_lo(float a, float b, unsigned int old) {
    return (unsigned int)__builtin_amdgcn_cvt_pk_fp8_f32(a, b, (int)old, false);
}
__device__ __forceinline__ unsigned int f2f8_hi(float a, float b, unsigned int old) {
    return (unsigned int)__builtin_amdgcn_cvt_pk_fp8_f32(a, b, (int)old, true);
}
__device__ __forceinline__ unsigned char f2f8s(float a) {
    return (unsigned char)(__builtin_amdgcn_cvt_pk_fp8_f32(a, a, 0, false) & 0xFF);
}

// ------------------------------------------------- prep
// Permuted byte order for fp8 rows: byte q holds col c(q) = (q&7)*16 + (q>>3).
// Wt1: bf16 [n][k] for layer-1 bf16 MFMA.
// Wt2p: fp8 [n][q] with k-rows permuted by the SAME c(q) as A1's byte order —
// joint k-permutation of A and B leaves the dot product invariant.
__global__ __launch_bounds__(256) void k_prep(const float* __restrict__ W1,
                                              const float* __restrict__ W2,
                                              const float* __restrict__ b1,
                                              const float* __restrict__ b2,
                                              unsigned short* __restrict__ Wt1,
                                              unsigned char* __restrict__ Wt2p,
                                              float* __restrict__ b1p,
                                              float* __restrict__ b2p,
                                              int* __restrict__ gcur) {
    int b = blockIdx.x, t = threadIdx.x;
    if (b < 128) {
        if (t < 128) {
            Wt1[b * 128 + t] = f2b(W1[t * 128 + b]);
        } else {
            int q = t - 128;
            int c = (q & 7) * 16 + (q >> 3);
            Wt2p[b * 128 + q] = f2f8s(W2[c * 128 + b]);
        }
    } else {
        if (t < NBK) gcur[t] = t * SLOT;
        if (t < 128) {
            int c = (t & 7) * 16 + (t >> 3);  // col held at permuted position t
            b1p[t] = b1[c];
            b2p[t] = b2[c];
        }
    }
}

// -------------------------------------------------------- two-phase binning
// LDS counting-sort (R17-verified): entries sorted into bucket order in LDS,
// then written out linearly (coalesced).
__global__ __launch_bounds__(256) void k_bin2(const int* __restrict__ row,
                                              const int* __restrict__ col,
                                              int* __restrict__ gcur,
                                              unsigned int* __restrict__ tmp) {
    __shared__ unsigned int ent[4000];
    __shared__ unsigned int srt[4000];
    __shared__ unsigned char bkt[4000];
    __shared__ unsigned char bky[4000];
    __shared__ int cnt[NBK];
    __shared__ int gbase[NBK];
    __shared__ int lbase[NBK];
    __shared__ int sh[256];
    int t = threadIdx.x;
    if (t < NBK) cnt[t] = 0;
    __syncthreads();
    const int q0 = blockIdx.x * 1000;  // int4 index base (4000 edges)
    const int4* col4 = (const int4*)col;
    const int4* row4 = (const int4*)row;
#pragma unroll
    for (int it = 0; it < 4; it++) {
        int idx = it * 256 + t;
        if (idx < 1000) {
            int4 c = col4[q0 + idx];
            int4 r = row4[q0 + idx];
            int d, b;
            d = c.x; b = d >> BSH; atomicAdd(&cnt[b], 1);
            ent[idx * 4 + 0] = ((unsigned int)(d & 511) << 17) | (unsigned int)r.x;
            bkt[idx * 4 + 0] = (unsigned char)b;
            d = c.y; b = d >> BSH; atomicAdd(&cnt[b], 1);
            ent[idx * 4 + 1] = ((unsigned int)(d & 511) << 17) | (unsigned int)r.y;
            bkt[idx * 4 + 1] = (unsigned char)b;
            d = c.z; b = d >> BSH; atomicAdd(&cnt[b], 1);
            ent[idx * 4 + 2] = ((unsigned int)(d & 511) << 17) | (unsigned int)r.z;
            bkt[idx * 4 + 2] = (unsigned char)b;
            d = c.w; b = d >> BSH; atomicAdd(&cnt[b], 1);
            ent[idx * 4 + 3] = ((unsigned int)(d & 511) << 17) | (unsigned int)r.w;
            bkt[idx * 4 + 3] = (unsigned char)b;
        }
    }
    __syncthreads();
    int v = (t < NBK) ? cnt[t] : 0;
    sh[t] = v;
    __syncthreads();
    for (int d = 1; d < 256; d <<= 1) {
        int u = (t >= d) ? sh[t - d] : 0;
        __syncthreads();
        sh[t] += u;
        __syncthreads();
    }
    if (t < NBK) {
        lbase[t] = sh[t] - v;
        gbase[t] = atomicAdd(&gcur[t], v);
        cnt[t] = sh[t] - v;  // becomes local cursor
    }
    __syncthreads();
#pragma unroll
    for (int it = 0; it < 16; it++) {
        int i = it * 256 + t;
        if (i < 4000) {
            int b = bkt[i];
            int p = atomicAdd(&cnt[b], 1);
            srt[p] = ent[i];
            bky[p] = (unsigned char)b;
        }
    }
    __syncthreads();
#pragma unroll
    for (int it = 0; it < 16; it++) {
        int i = it * 256 + t;
        if (i < 4000) {
            int b = bky[i];
            tmp[gbase[b] + (i - lbase[b])] = srt[i];
        }
    }
}

// -------------------------------------------------------- per-bucket CSR
__global__ __launch_bounds__(1024) void k_bucket(const unsigned int* __restrict__ tmp,
                                                 const int* __restrict__ gcur,
                                                 int* __restrict__ off,
                                                 int* __restrict__ degw,
                                                 float* __restrict__ dinv,
                                                 int* __restrict__ csr_src) {
    __shared__ int cnt[512];
    __shared__ int loff[512];
    __shared__ int sh[256];
    int b = blockIdx.x, t = threadIdx.x;
    int j0 = b << BSH;
    int nd = min(512, NN - j0);
    int rb = b * SLOT;
    int m = gcur[b] - rb;
    if (t < 512) cnt[t] = 0;
    __syncthreads();
    for (int i = t; i < m; i += 1024)
        atomicAdd(&cnt[tmp[rb + i] >> 17], 1);
    __syncthreads();
    int r0 = 0, r1 = 0, p0 = 0, ts = 0;
    if (t < 256) {
        r0 = cnt[2 * t]; r1 = cnt[2 * t + 1];
        p0 = (r0 + 3) & ~3;
        int p1 = (r1 + 3) & ~3;  // pad to 4-entry alignment
        ts = p0 + p1;
        sh[t] = ts;
    }
    __syncthreads();
    for (int d = 1; d < 256; d <<= 1) {
        int u = (t >= d && t < 256) ? sh[t - d] : 0;
        __syncthreads();
        if (t < 256) sh[t] += u;
        __syncthreads();
    }
    if (t < 256) {
        int ex = sh[t] - ts;
        loff[2 * t] = ex;
        loff[2 * t + 1] = ex + p0;
    }
    __syncthreads();
    for (int j = t; j < nd; j += 1024) {
        int o = rb + loff[j];
        int dg = cnt[j];
        off[j0 + j] = o;
        degw[j0 + j] = dg;
        dinv[j0 + j] = rsqrtf((float)(dg + 1));  // +1 self-loop
        cnt[j] = o;  // becomes cursor
    }
    __syncthreads();
    for (int i = t; i < m; i += 1024) {
        unsigned int e = tmp[rb + i];
        int d = e >> 17;
        int s = (int)(e & 0x1FFFFu);
        int p = atomicAdd(&cnt[d], 1);
        csr_src[p] = s;
    }
}

// ---------------------------------------------------------------- GEMM layer 1
// Hs8[r] = fp8( dinv[r] * (bf16(x) @ Wt1^T) row r ), PERMUTED bytes (q=n16*8+ct).
__global__ __launch_bounds__(256) void k_gemm1(const float* __restrict__ X,
                                               const unsigned short* __restrict__ Wt,
                                               const float* __restrict__ dinv,
                                               unsigned char* __restrict__ Hs8) {
    __shared__ __align__(16) unsigned short Ws[128 * 128];  // 32 KB
    int t = threadIdx.x;
#pragma unroll
    for (int i = 0; i < 8; i++) {
        int id = t + i * 256;
        int n = id >> 4, c = id & 15;
        *(short8*)((char*)Ws + n * 256 + ((c ^ (n & 15)) << 4)) =
            *(const short8*)(Wt + n * 128 + c * 8);
    }
    __syncthreads();

    int lane = t & 63, wid = t >> 6;
    int n16 = lane & 15, quad = lane >> 4;
    int row_base = blockIdx.x * 128 + wid * 32;

    short8 a[2][4];
#pragma unroll
    for (int rt = 0; rt < 2; rt++) {
        int r = row_base + rt * 16 + n16;
        if (r > NN - 1) r = NN - 1;
        const float* ap = X + (size_t)r * 128 + quad * 8;
#pragma unroll
        for (int ks = 0; ks < 4; ks++) {
            float4 v0 = *(const float4*)(ap + ks * 32);
            float4 v1 = *(const float4*)(ap + ks * 32 + 4);
            uint4 up;
            up.x = pack2(v0.x, v0.y); up.y = pack2(v0.z, v0.w);
            up.z = pack2(v1.x, v1.y); up.w = pack2(v1.z, v1.w);
            a[rt][ks] = *(short8*)&up;
        }
    }

    f32x4 acc[2][8];
#pragma unroll
    for (int rt = 0; rt < 2; rt++)
#pragma unroll
        for (int ct = 0; ct < 8; ct++)
            acc[rt][ct] = (f32x4){0.f, 0.f, 0.f, 0.f};

#pragma unroll
    for (int ks = 0; ks < 4; ks++) {
#pragma unroll
        for (int ct = 0; ct < 8; ct++) {
            short8 b = *(const short8*)((const char*)Ws +
                        (ct * 16 + n16) * 256 + ((((ks << 2) + quad) ^ n16) << 4));
            acc[0][ct] = __builtin_amdgcn_mfma_f32_16x16x32_bf16(a[0][ks], b, acc[0][ct], 0, 0, 0);
            acc[1][ct] = __builtin_amdgcn_mfma_f32_16x16x32_bf16(a[1][ks], b, acc[1][ct], 0, 0, 0);
        }
    }

#pragma unroll
    for (int rt = 0; rt < 2; rt++) {
#pragma unroll
        for (int reg = 0; reg < 4; reg++) {
            int row = row_base + rt * 16 + quad * 4 + reg;
            if (row < NN) {
                float di = dinv[row];
                unsigned int u0 = 0, u1 = 0;
                u0 = f2f8_lo(acc[rt][0][reg] * di, acc[rt][1][reg] * di, u0);
                u0 = f2f8_hi(acc[rt][2][reg] * di, acc[rt][3][reg] * di, u0);
                u1 = f2f8_lo(acc[rt][4][reg] * di, acc[rt][5][reg] * di, u1);
                u1 = f2f8_hi(acc[rt][6][reg] * di, acc[rt][7][reg] * di, u1);
                uint2 o; o.x = u0; o.y = u1;
                ((uint2*)(Hs8 + (size_t)row * 128))[n16] = o;
            }
        }
    }
}

// ---------------------------------------------------------------- GEMM layer 2
// fp8 x fp8 MFMA. A = A1 (fp8, permuted byte order); B = Wt2p (fp8, k-rows
// permuted by the same c(q)) -> joint k-permutation cancels in the dot product.
// LDS: 16 KB, XOR-8B-chunk swizzle (16 distinct banks per quad on b64 reads).
__global__ __launch_bounds__(256) void k_gemm2(const unsigned char* __restrict__ A8,
                                               const unsigned char* __restrict__ Wt2p,
                                               const float* __restrict__ dinv,
                                               unsigned char* __restrict__ Hs8) {
    __shared__ __align__(16) unsigned char Ws[128 * 128];  // 16 KB
    int t = threadIdx.x;
#pragma unroll
    for (int i = 0; i < 8; i++) {
        int id = t + i * 256;          // 2048 8-byte chunks
        int n = id >> 4, c = id & 15;
        *(uint2*)(Ws + n * 128 + ((c ^ (n & 15)) << 3)) =
            *(const uint2*)(Wt2p + n * 128 + c * 8);
    }
    __syncthreads();

    int lane = t & 63, wid = t >> 6;
    int n16 = lane & 15, quad = lane >> 4;
    int row_base = blockIdx.x * 128 + wid * 32;

    uint2 a[2][4];
#pragma unroll
    for (int rt = 0; rt < 2; rt++) {
        int r = row_base + rt * 16 + n16;
        if (r > NN - 1) r = NN - 1;
        const unsigned char* ap = A8 + (size_t)r * 128 + quad * 8;
#pragma unroll
        for (int ks = 0; ks < 4; ks++)
            a[rt][ks] = *(const uint2*)(ap + ks * 32);
    }

    f32x4 acc[2][8];
#pragma unroll
    for (int rt = 0; rt < 2; rt++)
#pragma unroll
        for (int ct = 0; ct < 8; ct++)
            acc[rt][ct] = (f32x4){0.f, 0.f, 0.f, 0.f};

#pragma unroll
    for (int ks = 0; ks < 4; ks++) {
        long a0 = __builtin_bit_cast(long, a[0][ks]);
        long a1 = __builtin_bit_cast(long, a[1][ks]);
#pragma unroll
        for (int ct = 0; ct < 8; ct++) {
            uint2 bv = *(const uint2*)(Ws + (ct * 16 + n16) * 128 +
                                       ((((ks << 2) + quad) ^ n16) << 3));
            long bb = __builtin_bit_cast(long, bv);
            acc[0][ct] = __builtin_amdgcn_mfma_f32_16x16x32_fp8_fp8(a0, bb, acc[0][ct], 0, 0, 0);
            acc[1][ct] = __builtin_amdgcn_mfma_f32_16x16x32_fp8_fp8(a1, bb, acc[1][ct], 0, 0, 0);
        }
    }

#pragma unroll
    for (int rt = 0; rt < 2; rt++) {
#pragma unroll
        for (int reg = 0; reg < 4; reg++) {
            int row = row_base + rt * 16 + quad * 4 + reg;
            if (row < NN) {
                float di = dinv[row];
                unsigned int u0 = 0, u1 = 0;
                u0 = f2f8_lo(acc[rt][0][reg] * di, acc[rt][1][reg] * di, u0);
                u0 = f2f8_hi(acc[rt][2][reg] * di, acc[rt][3][reg] * di, u0);
                u1 = f2f8_lo(acc[rt][4][reg] * di, acc[rt][5][reg] * di, u1);
                u1 = f2f8_hi(acc[rt][6][reg] * di, acc[rt][7][reg] * di, u1);
                uint2 o; o.x = u0; o.y = u1;
                ((uint2*)(Hs8 + (size_t)row * 128))[n16] = o;
            }
        }
    }
}

// ---------------------------------------------------------------- aggregation
// out[i] = relu( dinv[i] * (Hs[i] + sum_e Hs[src_e]) + bias ), fp8 permuted out.
// Single-round predicated gather (R16-verified); f32x2 packed accumulators
// (invites v_pk_add_f32 — halves the add count).
__global__ __launch_bounds__(256) void k_agg(const unsigned char* __restrict__ Hb,
                                             const int* __restrict__ off,
                                             const int* __restrict__ degw,
                                             const int* __restrict__ csr_src,
                                             const float* __restrict__ dinv,
                                             const float* __restrict__ biasp,
                                             unsigned char* __restrict__ outp) {
    int node = blockIdx.x * 4 + (threadIdx.x >> 6);
    int lane = threadIdx.x & 63;
    int sub = lane >> 4, li = lane & 15;
    unsigned loff = (unsigned)li * 8u;
    f32x2 A0 = {0.f, 0.f}, A1 = {0.f, 0.f}, A2 = {0.f, 0.f}, A3 = {0.f, 0.f};
#define LDH(idx) (*(const uint2*)(Hb + (unsigned)(idx) * 128u + loff))
#define ACC8(V) { \
        A0 += f8_2f<0>((V).x); A1 += f8_2f<1>((V).x); \
        A2 += f8_2f<0>((V).y); A3 += f8_2f<1>((V).y); }
    int deg = degw[node];
    int base = off[node];
    int slot = sub * 4;
    int4 iA = *(const int4*)(csr_src + base + slot);
    int4 iB;
    bool hasB = deg > 16;
    if (hasB) iB = *(const int4*)(csr_src + base + 16 + slot);
    uint2 v = {0, 0};
    if (sub == 0) v = LDH(node);  // self (already dinv-scaled)
    uint2 w0 = {0,0}, w1 = {0,0}, w2 = {0,0}, w3 = {0,0};
    uint2 w4 = {0,0}, w5 = {0,0}, w6 = {0,0}, w7 = {0,0};
    if (slot + 0 < deg) w0 = LDH(iA.x);
    if (slot + 1 < deg) w1 = LDH(iA.y);
    if (slot + 2 < deg) w2 = LDH(iA.z);
    if (slot + 3 < deg) w3 = LDH(iA.w);
    if (hasB) {
        if (slot + 16 < deg) w4 = LDH(iB.x);
        if (slot + 17 < deg) w5 = LDH(iB.y);
        if (slot + 18 < deg) w6 = LDH(iB.z);
        if (slot + 19 < deg) w7 = LDH(iB.w);
    }
    ACC8(v)
    ACC8(w0) ACC8(w1) ACC8(w2) ACC8(w3)
    if (hasB) { ACC8(w4) ACC8(w5) ACC8(w6) ACC8(w7) }
    if (deg > 32) {  // rare remainder
        int e = base + 32, e1 = base + deg;
        for (; e + 16 <= e1; e += 16) {
            int4 sv = *(const int4*)(csr_src + e + sub * 4);
            uint2 x0 = LDH(sv.x);
            uint2 x1 = LDH(sv.y);
            uint2 x2 = LDH(sv.z);
            uint2 x3 = LDH(sv.w);
            ACC8(x0) ACC8(x1) ACC8(x2) ACC8(x3)
        }
        for (; e + 8 <= e1; e += 8) {
            int2 sv = *(const int2*)(csr_src + e + sub * 2);
            uint2 xA = LDH(sv.x);
            uint2 xB = LDH(sv.y);
            ACC8(xA) ACC8(xB)
        }
        for (; e < e1; e += 4) {
            int ee = e + sub;
            if (ee < e1) {
                uint2 w = LDH(csr_src[ee]);
                ACC8(w)
            }
        }
    }
#undef ACC8
#undef LDH
#pragma unroll
    for (int d = 16; d <= 32; d <<= 1) {
        A0[0] += __shfl_xor(A0[0], d); A0[1] += __shfl_xor(A0[1], d);
        A1[0] += __shfl_xor(A1[0], d); A1[1] += __shfl_xor(A1[1], d);
        A2[0] += __shfl_xor(A2[0], d); A2[1] += __shfl_xor(A2[1], d);
        A3[0] += __shfl_xor(A3[0], d); A3[1] += __shfl_xor(A3[1], d);
    }
    if (sub == 0) {
        float di = dinv[node];
        const float4* b4 = (const float4*)biasp;  // permuted bias
        float4 bA = b4[li * 2], bB = b4[li * 2 + 1];
        float r0 = fmaxf(fmaf(di, A0[0], bA.x), 0.f);
        float r1 = fmaxf(fmaf(di, A0[1], bA.y), 0.f);
        float r2 = fmaxf(fmaf(di, A1[0], bA.z), 0.f);
        float r3 = fmaxf(fmaf(di, A1[1], bA.w), 0.f);
        float r4 = fmaxf(fmaf(di, A2[0], bB.x), 0.f);
        float r5 = fmaxf(fmaf(di, A2[1], bB.y), 0.f);
        float r6 = fmaxf(fmaf(di, A3[0], bB.z), 0.f);
        float r7 = fmaxf(fmaf(di, A3[1], bB.w), 0.f);
        unsigned int u0 = 0, u1 = 0;
        u0 = f2f8_lo(r0, r1, u0); u0 = f2f8_hi(r2, r3, u0);
        u1 = f2f8_lo(r4, r5, u1); u1 = f2f8_hi(r6, r7, u1);
        uint2 o; o.x = u0; o.y = u1;
        *(uint2*)(outp + (unsigned)node * 128u + loff) = o;
    }
}

// ------------------------------------------------- fused mean-pool + head MLP
// A2: fp8 permuted. part[] indexed by permuted byte q; hc[] unpermutes.
__global__ __launch_bounds__(256) void k_poolhead(const unsigned char* __restrict__ A,
                                                  const int* __restrict__ batch,
                                                  const float* __restrict__ u,
                                                  const float* __restrict__ Wh1,
                                                  const float* __restrict__ bh1,
                                                  const float* __restrict__ Wh2,
                                                  const float* __restrict__ bh2,
                                                  float* __restrict__ out) {
    int g = blockIdx.x, t = threadIdx.x;
    int lo = 0, hi = NN;
    while (lo < hi) { int m = (lo + hi) >> 1; if (batch[m] < g) lo = m + 1; else hi = m; }
    int start = lo;
    hi = NN;
    while (lo < hi) { int m = (lo + hi) >> 1; if (batch[m] < g + 1) lo = m + 1; else hi = m; }
    int end = lo;

    int li = t & 7;    // 16-byte chunk of the 128B row
    int ri = t >> 3;   // row offset 0..31
    float acc[16];
#pragma unroll
    for (int j = 0; j < 16; j++) acc[j] = 0.f;
    f32x2 p;
    for (int i = start + ri; i < end; i += 32) {
        uint4 v = ((const uint4*)A)[(size_t)i * 8 + li];
#define UP(VV, base) p = f8_2f<0>(VV); acc[base] += p.x; acc[base+1] += p.y; \
                     p = f8_2f<1>(VV); acc[base+2] += p.x; acc[base+3] += p.y;
        UP(v.x, 0) UP(v.y, 4) UP(v.z, 8) UP(v.w, 12)
#undef UP
    }
#pragma unroll
    for (int j = 0; j < 16; j++) {
        acc[j] += __shfl_xor(acc[j], 8);
        acc[j] += __shfl_xor(acc[j], 16);
        acc[j] += __shfl_xor(acc[j], 32);
    }
    __shared__ float part[4][128];
    __shared__ float hc[192];
    __shared__ float tt[128];
    int w = t >> 6;
    if ((t & 63) < 8) {
#pragma unroll
        for (int j = 0; j < 16; j++) part[w][li * 16 + j] = acc[j];  // index = byte q
    }
    __syncthreads();
    float cntf = (float)max(end - start, 1);
    if (t < 128) {
        int q = (t & 15) * 8 + (t >> 4);  // permuted position of col t
        hc[t] = (part[0][q] + part[1][q] + part[2][q] + part[3][q]) / cntf;
    } else if (t < 192) {
        hc[t] = u[g * 64 + (t - 128)];
    }
    __syncthreads();
    if (t < 128) {
        float a2 = bh1[t];
        for (int k = 0; k < 192; k++) a2 = fmaf(hc[k], Wh1[k * 128 + t], a2);
        tt[t] = fmaxf(a2, 0.f);
    }
    __syncthreads();
    if (t < 2) {
        float o = bh2[t];
        for (int c2 = 0; c2 < 128; c2++) o = fmaf(tt[c2], Wh2[c2 * 2 + t], o);
        out[g * 2 + t] = o;
    }
}

// ---------------------------------------------------------------- launcher
extern "C" void kernel_launch(void* const* d_in, const int* in_sizes, int n_in,
                              void* d_out, int out_size, void* d_ws, size_t ws_size,
                              hipStream_t stream) {
    const float* x   = (const float*)d_in[0];
    const int*   ei  = (const int*)d_in[1];
    const int*   row = ei;        // edge_index[0] = src
    const int*   col = ei + NE;   // edge_index[1] = dst
    const float* u   = (const float*)d_in[2];
    const int*   batch = (const int*)d_in[3];
    const float* W1  = (const float*)d_in[5];
    const float* b1  = (const float*)d_in[6];
    const float* W2  = (const float*)d_in[7];
    const float* b2  = (const float*)d_in[8];
    const float* Wh1 = (const float*)d_in[9];
    const float* bh1 = (const float*)d_in[10];
    const float* Wh2 = (const float*)d_in[11];
    const float* bh2 = (const float*)d_in[12];
    float* out = (float*)d_out;

    char* ws = (char*)d_ws;
    size_t o = 0;
    auto alloc = [&](size_t bytes) -> void* {
        void* p = ws + o;
        o += (bytes + 511) & ~(size_t)511;
        return p;
    };
    unsigned char*  Hs8 = (unsigned char*)alloc((size_t)NN * 128);   // fp8 permuted
    unsigned char*  A1b = (unsigned char*)alloc((size_t)NN * 128);   // fp8 permuted
    unsigned char*  A2b = (unsigned char*)alloc((size_t)NN * 128);   // fp8 permuted
    unsigned short* Wt1 = (unsigned short*)alloc((size_t)128 * 128 * 2);
    unsigned char*  Wt2p= (unsigned char*)alloc((size_t)128 * 128);
    float* b1p    = (float*)alloc((size_t)128 * 4);
    float* b2p    = (float*)alloc((size_t)128 * 4);
    float* dinv   = (float*)alloc((size_t)NN * 4);
    int*   off    = (int*)alloc((size_t)NN * 4);
    int*   degw   = (int*)alloc((size_t)NN * 4);
    int*   csr_src= (int*)alloc((size_t)NBK * SLOT * 4 + 256);  // +slack for predicated overread
    unsigned int* tmp = (unsigned int*)alloc((size_t)NBK * SLOT * 4);
    int*   gcur   = (int*)alloc((size_t)256 * 4);

    // --- prep (W transforms + cursors + permuted biases) & CSR build ---
    k_prep<<<129, 256, 0, stream>>>(W1, W2, b1, b2, Wt1, Wt2p, b1p, b2p, gcur);
    k_bin2<<<400, 256, 0, stream>>>(row, col, gcur, tmp);
    k_bucket<<<NBK, 1024, 0, stream>>>(tmp, gcur, off, degw, dinv, csr_src);

    // --- layer 1 (f32 input, bf16 MFMA; fp8 H) ---
    k_gemm1<<<cdiv(NN, 128), 256, 0, stream>>>(x, Wt1, dinv, Hs8);
    k_agg<<<NN / 4, 256, 0, stream>>>(Hs8, off, degw, csr_src, dinv, b1p, A1b);
    // --- layer 2 (fp8 input, fp8 MFMA) ---
    k_gemm2<<<cdiv(NN, 128), 256, 0, stream>>>(A1b, Wt2p, dinv, Hs8);
    k_agg<<<NN / 4, 256, 0, stream>>>(Hs8, off, degw, csr_src, dinv, b2p, A2b);

    // --- fused mean pool + head ---
    k_poolhead<<<NG, 256, 0, stream>>>(A2b, batch, u, Wh1, bh1, Wh2, bh2, out);
}